// Round 2
// baseline (541.741 us; speedup 1.0000x reference)
//
#include <hip/hip_runtime.h>
#include <hip/hip_bf16.h>

// Problem dims (fixed by the reference)
#define BB 4
#define TT 2048
#define HH 1024
#define NHH 16
#define DKK 64
// M = BB*TT = 8192, K = N = HH = 1024

typedef __attribute__((ext_vector_type(8))) short bf16x8;
typedef __attribute__((ext_vector_type(4))) float f32x4;

__device__ __forceinline__ unsigned short f2bf(float f) {
    union { float f; unsigned u; } v; v.f = f;
    unsigned r = v.u + 0x7fffu + ((v.u >> 16) & 1u);  // RNE
    return (unsigned short)(r >> 16);
}

// ---------------- fp32 -> bf16 elementwise convert (vector x4) ----------------
__global__ __launch_bounds__(256) void cvt_kernel(const float* __restrict__ in,
                                                  unsigned short* __restrict__ out, int n4) {
    int i = blockIdx.x * blockDim.x + threadIdx.x;
    if (i < n4) {
        float4 v = reinterpret_cast<const float4*>(in)[i];
        union { unsigned short u[4]; unsigned long long ll; } o;
        o.u[0] = f2bf(v.x); o.u[1] = f2bf(v.y); o.u[2] = f2bf(v.z); o.u[3] = f2bf(v.w);
        reinterpret_cast<unsigned long long*>(out)[i] = o.ll;
    }
}

// ---------------- weight transpose + convert: Wt[n][k] = (bf16)W[k][n], 1024x1024 ----------------
__global__ __launch_bounds__(256) void wtcvt_kernel(const float* __restrict__ W,
                                                    unsigned short* __restrict__ Wt) {
    __shared__ float t[32][33];
    int bx = blockIdx.x * 32, by = blockIdx.y * 32;
    int tx = threadIdx.x, ty = threadIdx.y;   // block (32,8)
#pragma unroll
    for (int i = 0; i < 32; i += 8)
        t[ty + i][tx] = W[(size_t)(by + ty + i) * HH + bx + tx];
    __syncthreads();
#pragma unroll
    for (int i = 0; i < 32; i += 8)
        Wt[(size_t)(bx + ty + i) * HH + by + tx] = f2bf(t[tx][ty + i]);
}

// ---------------- MFMA GEMM: C(MxN) = A(MxK,bf16) @ Wt(NxK,bf16)^T + bias, epilogues ----------------
// EPI: 1=relu->bf16  2=source-mask->bf16  3=head-split store (Q/K)  4=transposed-head (V)  5=+resid, fp32 out
template <int EPI>
__global__ __launch_bounds__(256) void gemm_kernel(
    const unsigned short* __restrict__ A, const unsigned short* __restrict__ Bt,
    const float* __restrict__ bias, unsigned short* __restrict__ Cb,
    float* __restrict__ Cf, const float* __restrict__ resid,
    const int* __restrict__ slen, int M, int N, int K) {
    __shared__ unsigned short As[64 * 72];
    __shared__ unsigned short Bs[64 * 72];
    int tid = threadIdx.x, lane = tid & 63, w = tid >> 6;
    int wr = (w >> 1) * 32, wc = (w & 1) * 32;
    int by = blockIdx.y * 64, bx = blockIdx.x * 64;

    f32x4 acc[2][2] = {};
    for (int k0 = 0; k0 < K; k0 += 64) {
        __syncthreads();
#pragma unroll
        for (int c = 0; c < 2; c++) {
            int idx = tid + c * 256;
            int r = idx >> 3, kc = (idx & 7) * 8;
            *(bf16x8*)&As[r * 72 + kc] = *(const bf16x8*)&A[(size_t)(by + r) * K + k0 + kc];
            *(bf16x8*)&Bs[r * 72 + kc] = *(const bf16x8*)&Bt[(size_t)(bx + r) * K + k0 + kc];
        }
        __syncthreads();
#pragma unroll
        for (int kk = 0; kk < 2; kk++) {
            bf16x8 a[2], b[2];
#pragma unroll
            for (int i = 0; i < 2; i++)
                a[i] = *(bf16x8*)&As[(wr + i * 16 + (lane & 15)) * 72 + kk * 32 + (lane >> 4) * 8];
#pragma unroll
            for (int j = 0; j < 2; j++)
                b[j] = *(bf16x8*)&Bs[(wc + j * 16 + (lane & 15)) * 72 + kk * 32 + (lane >> 4) * 8];
#pragma unroll
            for (int i = 0; i < 2; i++)
#pragma unroll
                for (int j = 0; j < 2; j++)
                    acc[i][j] = __builtin_amdgcn_mfma_f32_16x16x32_bf16(a[i], b[j], acc[i][j], 0, 0, 0);
        }
    }

    int sl = 0;
    if constexpr (EPI == 2) sl = slen[by >> 11];  // 64-row tile never crosses a batch (2048 % 64 == 0)
#pragma unroll
    for (int i = 0; i < 2; i++)
#pragma unroll
        for (int j = 0; j < 2; j++)
#pragma unroll
            for (int r = 0; r < 4; r++) {
                int row = by + wr + i * 16 + (lane >> 4) * 4 + r;
                int col = bx + wc + j * 16 + (lane & 15);
                float v = acc[i][j][r] + bias[col];
                if constexpr (EPI == 1) v = fmaxf(v, 0.f);
                if constexpr (EPI == 2) { int t = row & (TT - 1); if (t >= sl) v = 0.f; }
                if constexpr (EPI == 1 || EPI == 2) {
                    Cb[(size_t)row * N + col] = f2bf(v);
                } else if constexpr (EPI == 3) {
                    int b = row >> 11, t = row & (TT - 1), h = col >> 6, d = col & 63;
                    Cb[((size_t)((b * NHH + h) * TT + t)) * DKK + d] = f2bf(v);
                } else if constexpr (EPI == 4) {
                    int b = row >> 11, t = row & (TT - 1), h = col >> 6, d = col & 63;
                    Cb[((size_t)((b * NHH + h) * DKK + d)) * TT + t] = f2bf(v);
                } else if constexpr (EPI == 5) {
                    Cf[(size_t)row * N + col] = v + resid[(size_t)row * N + col];
                }
            }
}

// ---------------- flash attention: block = (b, h, 64 q-rows), 4 waves x 16 q-rows ----------------
__global__ __launch_bounds__(256) void attn_kernel(
    const unsigned short* __restrict__ Q, const unsigned short* __restrict__ K,
    const unsigned short* __restrict__ Vt, const int* __restrict__ slen,
    unsigned short* __restrict__ ctx) {
    __shared__ unsigned short Ks[64 * 72];        // [kv][dk] padded
    __shared__ unsigned short Vs[64 * 72];        // [dk][kv] padded
    __shared__ unsigned short Pl[4][16 * 72];     // per-wave P tile [q][kv] padded
    int tid = threadIdx.x, lane = tid & 63, w = tid >> 6;
    int b = blockIdx.z, h = blockIdx.y, q0 = blockIdx.x * 64;
    size_t bh = (size_t)(b * NHH + h);
    int sl = slen[b];

    bf16x8 qf[2];
    int qrow = q0 + w * 16 + (lane & 15);
#pragma unroll
    for (int half = 0; half < 2; half++)
        qf[half] = *(const bf16x8*)&Q[(bh * TT + qrow) * DKK + half * 32 + (lane >> 4) * 8];

    float m_[4], l_[4];
    f32x4 o[4] = {};
#pragma unroll
    for (int r = 0; r < 4; r++) { m_[r] = -INFINITY; l_[r] = 0.f; }

    for (int kt = 0; kt < TT; kt += 64) {
        __syncthreads();
#pragma unroll
        for (int c = 0; c < 2; c++) {
            int idx = tid + c * 256;
            int r = idx >> 3, kc = (idx & 7) * 8;
            *(bf16x8*)&Ks[r * 72 + kc] = *(const bf16x8*)&K[(bh * TT + kt + r) * DKK + kc];
            *(bf16x8*)&Vs[r * 72 + kc] = *(const bf16x8*)&Vt[(bh * DKK + r) * TT + kt + kc];
        }
        __syncthreads();

        f32x4 s[4] = {};
#pragma unroll
        for (int j = 0; j < 4; j++)
#pragma unroll
            for (int half = 0; half < 2; half++) {
                bf16x8 kf = *(bf16x8*)&Ks[(j * 16 + (lane & 15)) * 72 + half * 32 + (lane >> 4) * 8];
                s[j] = __builtin_amdgcn_mfma_f32_16x16x32_bf16(qf[half], kf, s[j], 0, 0, 0);
            }

        float mb[4];
#pragma unroll
        for (int j = 0; j < 4; j++) {
            int kvi = kt + j * 16 + (lane & 15);
            mb[j] = (kvi < sl) ? 0.f : -10000.f;
        }

        float p[4][4];
#pragma unroll
        for (int r = 0; r < 4; r++) {
            float tmax = -INFINITY;
#pragma unroll
            for (int j = 0; j < 4; j++) {
                s[j][r] = s[j][r] * 0.125f + mb[j];
                tmax = fmaxf(tmax, s[j][r]);
            }
#pragma unroll
            for (int msk = 1; msk < 16; msk <<= 1) tmax = fmaxf(tmax, __shfl_xor(tmax, msk));
            float mn = fmaxf(m_[r], tmax);
            float alpha = __expf(m_[r] - mn);
            float ps = 0.f;
#pragma unroll
            for (int j = 0; j < 4; j++) { p[j][r] = __expf(s[j][r] - mn); ps += p[j][r]; }
#pragma unroll
            for (int msk = 1; msk < 16; msk <<= 1) ps += __shfl_xor(ps, msk);
            l_[r] = l_[r] * alpha + ps;
            m_[r] = mn;
#pragma unroll
            for (int g = 0; g < 4; g++) o[g][r] *= alpha;
        }
        // P -> per-wave LDS (re-fragment for PV's A-operand); same-wave dep, compiler orders lgkmcnt
#pragma unroll
        for (int r = 0; r < 4; r++)
#pragma unroll
            for (int j = 0; j < 4; j++)
                Pl[w][((lane >> 4) * 4 + r) * 72 + j * 16 + (lane & 15)] = f2bf(p[j][r]);

#pragma unroll
        for (int g = 0; g < 4; g++)
#pragma unroll
            for (int half = 0; half < 2; half++) {
                bf16x8 pf = *(bf16x8*)&Pl[w][(lane & 15) * 72 + half * 32 + (lane >> 4) * 8];
                bf16x8 vf = *(bf16x8*)&Vs[(g * 16 + (lane & 15)) * 72 + half * 32 + (lane >> 4) * 8];
                o[g] = __builtin_amdgcn_mfma_f32_16x16x32_bf16(pf, vf, o[g], 0, 0, 0);
            }
    }
#pragma unroll
    for (int g = 0; g < 4; g++)
#pragma unroll
        for (int r = 0; r < 4; r++) {
            int t = q0 + w * 16 + (lane >> 4) * 4 + r;
            int col = h * DKK + g * 16 + (lane & 15);
            float v = o[g][r] / l_[r];
            ctx[((size_t)(b * TT + t)) * HH + col] = f2bf(v);
        }
}

// ---------------- row LayerNorm in-place on d_out (fp32), eps=1e-12 ----------------
__global__ __launch_bounds__(256) void ln_kernel(float* __restrict__ x,
                                                 const float* __restrict__ gam,
                                                 const float* __restrict__ bet) {
    int row = blockIdx.x, tid = threadIdx.x;
    float4 v = reinterpret_cast<float4*>(x)[(size_t)row * 256 + tid];
    float s = v.x + v.y + v.z + v.w;
#pragma unroll
    for (int m = 1; m < 64; m <<= 1) s += __shfl_xor(s, m);
    __shared__ float red[4], red2[4];
    if ((tid & 63) == 0) red[tid >> 6] = s;
    __syncthreads();
    float mean = (red[0] + red[1] + red[2] + red[3]) * (1.f / 1024.f);
    float dx0 = v.x - mean, dx1 = v.y - mean, dx2 = v.z - mean, dx3 = v.w - mean;
    float ss = dx0 * dx0 + dx1 * dx1 + dx2 * dx2 + dx3 * dx3;
#pragma unroll
    for (int m = 1; m < 64; m <<= 1) ss += __shfl_xor(ss, m);
    if ((tid & 63) == 0) red2[tid >> 6] = ss;
    __syncthreads();
    float var = (red2[0] + red2[1] + red2[2] + red2[3]) * (1.f / 1024.f);
    float rs = rsqrtf(var + 1e-12f);
    int c = tid * 4;
    float4 ov;
    ov.x = dx0 * rs * gam[c + 0] + bet[c + 0];
    ov.y = dx1 * rs * gam[c + 1] + bet[c + 1];
    ov.z = dx2 * rs * gam[c + 2] + bet[c + 2];
    ov.w = dx3 * rs * gam[c + 3] + bet[c + 3];
    reinterpret_cast<float4*>(x)[(size_t)row * 256 + tid] = ov;
}

extern "C" void kernel_launch(void* const* d_in, const int* in_sizes, int n_in,
                              void* d_out, int out_size, void* d_ws, size_t ws_size,
                              hipStream_t stream) {
    const float* hid  = (const float*)d_in[0];
    const float* src  = (const float*)d_in[1];
    const int* slen   = (const int*)d_in[2];   // harness passes integers as int32
    const float* Wq  = (const float*)d_in[3];  const float* bq  = (const float*)d_in[4];
    const float* Wk  = (const float*)d_in[5];  const float* bk  = (const float*)d_in[6];
    const float* Wv  = (const float*)d_in[7];  const float* bv  = (const float*)d_in[8];
    const float* Wd  = (const float*)d_in[9];  const float* bd  = (const float*)d_in[10];
    const float* Wp1 = (const float*)d_in[11]; const float* bp1 = (const float*)d_in[12];
    const float* Wp2 = (const float*)d_in[13]; const float* bp2 = (const float*)d_in[14];
    const float* lng = (const float*)d_in[15]; const float* lnb = (const float*)d_in[16];

    // Workspace layout (bytes). Needs 92 MB.
    char* ws = (char*)d_ws;
    const size_t MB = 1ull << 20;
    unsigned short* Wqt  = (unsigned short*)(ws + 0 * MB);
    unsigned short* Wkt  = (unsigned short*)(ws + 2 * MB);
    unsigned short* Wvt  = (unsigned short*)(ws + 4 * MB);
    unsigned short* Wdt  = (unsigned short*)(ws + 6 * MB);
    unsigned short* Wp1t = (unsigned short*)(ws + 8 * MB);
    unsigned short* Wp2t = (unsigned short*)(ws + 10 * MB);
    unsigned short* hidb = (unsigned short*)(ws + 12 * MB);  // later aliased as Kb
    unsigned short* srcb = (unsigned short*)(ws + 28 * MB);  // later aliased as ctx
    unsigned short* Ptmp = (unsigned short*)(ws + 44 * MB);  // later aliased as Vtb
    unsigned short* Pb   = (unsigned short*)(ws + 60 * MB);
    unsigned short* Qb   = (unsigned short*)(ws + 76 * MB);
    unsigned short* Kb   = hidb;
    unsigned short* Vtb  = Ptmp;
    unsigned short* ctxb = srcb;

    dim3 tb(32, 8);
    wtcvt_kernel<<<dim3(32, 32), tb, 0, stream>>>(Wq, Wqt);
    wtcvt_kernel<<<dim3(32, 32), tb, 0, stream>>>(Wk, Wkt);
    wtcvt_kernel<<<dim3(32, 32), tb, 0, stream>>>(Wv, Wvt);
    wtcvt_kernel<<<dim3(32, 32), tb, 0, stream>>>(Wd, Wdt);
    wtcvt_kernel<<<dim3(32, 32), tb, 0, stream>>>(Wp1, Wp1t);
    wtcvt_kernel<<<dim3(32, 32), tb, 0, stream>>>(Wp2, Wp2t);

    const int n4 = (BB * TT * HH) / 4;  // 2M float4s
    cvt_kernel<<<n4 / 256, 256, 0, stream>>>(hid, hidb, n4);
    cvt_kernel<<<n4 / 256, 256, 0, stream>>>(src, srcb, n4);

    dim3 gg(HH / 64, (BB * TT) / 64);  // (16, 128)
    // P = mask(relu(src@Wp1+bp1)@Wp2+bp2)
    gemm_kernel<1><<<gg, 256, 0, stream>>>(srcb, Wp1t, bp1, Ptmp, nullptr, nullptr, nullptr, BB * TT, HH, HH);
    gemm_kernel<2><<<gg, 256, 0, stream>>>(Ptmp, Wp2t, bp2, Pb, nullptr, nullptr, slen, BB * TT, HH, HH);
    // Q,K head-split; V transposed-head
    gemm_kernel<3><<<gg, 256, 0, stream>>>(hidb, Wqt, bq, Qb, nullptr, nullptr, nullptr, BB * TT, HH, HH);
    gemm_kernel<3><<<gg, 256, 0, stream>>>(Pb, Wkt, bk, Kb, nullptr, nullptr, nullptr, BB * TT, HH, HH);
    gemm_kernel<4><<<gg, 256, 0, stream>>>(Pb, Wvt, bv, Vtb, nullptr, nullptr, nullptr, BB * TT, HH, HH);
    // attention -> ctx (B,T,H) bf16
    attn_kernel<<<dim3(TT / 64, NHH, BB), 256, 0, stream>>>(Qb, Kb, Vtb, slen, ctxb);
    // x = ctx@Wd + bd + hidden -> d_out fp32
    gemm_kernel<5><<<gg, 256, 0, stream>>>(ctxb, Wdt, bd, nullptr, (float*)d_out, hid, nullptr, BB * TT, HH, HH);
    // LayerNorm in place
    ln_kernel<<<BB * TT, 256, 0, stream>>>((float*)d_out, lng, lnb);
}

// Round 3
// 347.545 us; speedup vs baseline: 1.5588x; 1.5588x over previous
//
#include <hip/hip_runtime.h>
#include <hip/hip_bf16.h>

// Problem dims (fixed by the reference)
#define BB 4
#define TT 2048
#define HH 1024
#define NHH 16
#define DKK 64
// M = BB*TT = 8192, K = N = HH = 1024

typedef __attribute__((ext_vector_type(8))) short bf16x8;
typedef __attribute__((ext_vector_type(4))) float f32x4;

__device__ __forceinline__ unsigned short f2bf(float f) {
    union { float f; unsigned u; } v; v.f = f;
    unsigned r = v.u + 0x7fffu + ((v.u >> 16) & 1u);  // RNE
    return (unsigned short)(r >> 16);
}

// async global->LDS, 16B per lane; LDS dest must be linear in lane order
__device__ __forceinline__ void gload_lds16(const unsigned short* g, unsigned short* l) {
    __builtin_amdgcn_global_load_lds(
        (const __attribute__((address_space(1))) unsigned int*)g,
        (__attribute__((address_space(3))) unsigned int*)l, 16, 0, 0);
}

// ---------------- fp32 -> bf16 elementwise convert (vector x4) ----------------
__global__ __launch_bounds__(256) void cvt_kernel(const float* __restrict__ in,
                                                  unsigned short* __restrict__ out, int n4) {
    int i = blockIdx.x * blockDim.x + threadIdx.x;
    if (i < n4) {
        float4 v = reinterpret_cast<const float4*>(in)[i];
        union { unsigned short u[4]; unsigned long long ll; } o;
        o.u[0] = f2bf(v.x); o.u[1] = f2bf(v.y); o.u[2] = f2bf(v.z); o.u[3] = f2bf(v.w);
        reinterpret_cast<unsigned long long*>(out)[i] = o.ll;
    }
}

// ---------------- weight transpose + convert: Wt[n][k] = (bf16)W[k][n], 1024x1024 ----------------
__global__ __launch_bounds__(256) void wtcvt_kernel(const float* __restrict__ W,
                                                    unsigned short* __restrict__ Wt) {
    __shared__ float t[32][33];
    int bx = blockIdx.x * 32, by = blockIdx.y * 32;
    int tx = threadIdx.x, ty = threadIdx.y;   // block (32,8)
#pragma unroll
    for (int i = 0; i < 32; i += 8)
        t[ty + i][tx] = W[(size_t)(by + ty + i) * HH + bx + tx];
    __syncthreads();
#pragma unroll
    for (int i = 0; i < 32; i += 8)
        Wt[(size_t)(bx + ty + i) * HH + by + tx] = f2bf(t[tx][ty + i]);
}

// ---------------- MFMA GEMM (m97 structure): 128x128 tile, BK=64, global_load_lds w=16 ----------------
// EPI: 1=relu->bf16  2=source-mask->bf16  3=head-split store (Q/K)  4=transposed-head (V)  5=+resid, fp32 out
template <int EPI>
__global__ __launch_bounds__(256) void gemm_kernel(
    const unsigned short* __restrict__ A, const unsigned short* __restrict__ Bt,
    const float* __restrict__ bias, unsigned short* __restrict__ Cb,
    float* __restrict__ Cf, const float* __restrict__ resid,
    const int* __restrict__ slen, int M, int N, int K) {
    __shared__ unsigned short As[128 * 64];   // [row][k] linear (global_load_lds needs no pad)
    __shared__ unsigned short Bs[128 * 64];
    int tid = threadIdx.x, lane = tid & 63, w = tid >> 6;
    int wr = (w >> 1) * 64, wc = (w & 1) * 64;     // wave's 64x64 output quadrant
    int by = blockIdx.y * 128, bx = blockIdx.x * 128;

    f32x4 acc[4][4] = {};
    for (int k0 = 0; k0 < K; k0 += 64) {
        __syncthreads();
        // stage 128x64 bf16 A and B tiles: 1024 chunks x 16B each; 4 chunks/thread
#pragma unroll
        for (int c = 0; c < 4; c++) {
            int idx = c * 256 + tid;              // lane-consecutive within each wave
            int r = idx >> 3, col = (idx & 7) * 8;
            gload_lds16(&A[(size_t)(by + r) * K + k0 + col], &As[idx * 8]);
            gload_lds16(&Bt[(size_t)(bx + r) * K + k0 + col], &Bs[idx * 8]);
        }
        __syncthreads();  // compiler drains vmcnt(0) here (global_load_lds complete)
#pragma unroll
        for (int kk = 0; kk < 2; kk++) {
            bf16x8 a[4], b[4];
#pragma unroll
            for (int i = 0; i < 4; i++)
                a[i] = *(bf16x8*)&As[(wr + i * 16 + (lane & 15)) * 64 + kk * 32 + (lane >> 4) * 8];
#pragma unroll
            for (int j = 0; j < 4; j++)
                b[j] = *(bf16x8*)&Bs[(wc + j * 16 + (lane & 15)) * 64 + kk * 32 + (lane >> 4) * 8];
#pragma unroll
            for (int i = 0; i < 4; i++)
#pragma unroll
                for (int j = 0; j < 4; j++)
                    acc[i][j] = __builtin_amdgcn_mfma_f32_16x16x32_bf16(a[i], b[j], acc[i][j], 0, 0, 0);
        }
    }

    int sl = 0;
    if constexpr (EPI == 2) sl = slen[by >> 11];  // 128-row tile never crosses a batch (2048 % 128 == 0)
#pragma unroll
    for (int i = 0; i < 4; i++)
#pragma unroll
        for (int j = 0; j < 4; j++)
#pragma unroll
            for (int r = 0; r < 4; r++) {
                int row = by + wr + i * 16 + (lane >> 4) * 4 + r;
                int col = bx + wc + j * 16 + (lane & 15);
                float v = acc[i][j][r] + bias[col];
                if constexpr (EPI == 1) v = fmaxf(v, 0.f);
                if constexpr (EPI == 2) { int t = row & (TT - 1); if (t >= sl) v = 0.f; }
                if constexpr (EPI == 1 || EPI == 2) {
                    Cb[(size_t)row * N + col] = f2bf(v);
                } else if constexpr (EPI == 3) {
                    int b = row >> 11, t = row & (TT - 1), h = col >> 6, d = col & 63;
                    Cb[((size_t)((b * NHH + h) * TT + t)) * DKK + d] = f2bf(v);
                } else if constexpr (EPI == 4) {
                    int b = row >> 11, t = row & (TT - 1), h = col >> 6, d = col & 63;
                    Cb[((size_t)((b * NHH + h) * DKK + d)) * TT + t] = f2bf(v);
                } else if constexpr (EPI == 5) {
                    Cf[(size_t)row * N + col] = v + resid[(size_t)row * N + col];
                }
            }
}

// ---------------- flash attention: block = (b, h, 64 q-rows), 4 waves x 16 q-rows ----------------
// Skips fully-masked KV tiles: positions >= source_len carry -10000 bias -> exp()==0 exactly in
// fp32, so they contribute nothing. sl==0: P==0 -> every v row == bv, any prob dist returns bv.
__global__ __launch_bounds__(256) void attn_kernel(
    const unsigned short* __restrict__ Q, const unsigned short* __restrict__ K,
    const unsigned short* __restrict__ Vt, const int* __restrict__ slen,
    unsigned short* __restrict__ ctx) {
    __shared__ unsigned short Ks[64 * 72];        // [kv][dk] padded
    __shared__ unsigned short Vs[64 * 72];        // [dk][kv] padded
    __shared__ unsigned short Pl[4][16 * 72];     // per-wave P tile [q][kv] padded
    int tid = threadIdx.x, lane = tid & 63, w = tid >> 6;
    int b = blockIdx.z, h = blockIdx.y, q0 = blockIdx.x * 64;
    size_t bh = (size_t)(b * NHH + h);
    int sl = slen[b];
    int ktend = ((sl + 63) >> 6) << 6;
    if (ktend == 0) ktend = 64;                   // all-masked: one tile, uniform softmax -> bv

    bf16x8 qf[2];
    int qrow = q0 + w * 16 + (lane & 15);
#pragma unroll
    for (int half = 0; half < 2; half++)
        qf[half] = *(const bf16x8*)&Q[(bh * TT + qrow) * DKK + half * 32 + (lane >> 4) * 8];

    float m_[4], l_[4];
    f32x4 o[4] = {};
#pragma unroll
    for (int r = 0; r < 4; r++) { m_[r] = -INFINITY; l_[r] = 0.f; }

    for (int kt = 0; kt < ktend; kt += 64) {
        __syncthreads();
#pragma unroll
        for (int c = 0; c < 2; c++) {
            int idx = tid + c * 256;
            int r = idx >> 3, kc = (idx & 7) * 8;
            *(bf16x8*)&Ks[r * 72 + kc] = *(const bf16x8*)&K[(bh * TT + kt + r) * DKK + kc];
            *(bf16x8*)&Vs[r * 72 + kc] = *(const bf16x8*)&Vt[(bh * DKK + r) * TT + kt + kc];
        }
        __syncthreads();

        f32x4 s[4] = {};
#pragma unroll
        for (int j = 0; j < 4; j++)
#pragma unroll
            for (int half = 0; half < 2; half++) {
                bf16x8 kf = *(bf16x8*)&Ks[(j * 16 + (lane & 15)) * 72 + half * 32 + (lane >> 4) * 8];
                s[j] = __builtin_amdgcn_mfma_f32_16x16x32_bf16(qf[half], kf, s[j], 0, 0, 0);
            }

        float mb[4];
#pragma unroll
        for (int j = 0; j < 4; j++) {
            int kvi = kt + j * 16 + (lane & 15);
            mb[j] = (kvi < sl) ? 0.f : -10000.f;
        }

        float p[4][4];
#pragma unroll
        for (int r = 0; r < 4; r++) {
            float tmax = -INFINITY;
#pragma unroll
            for (int j = 0; j < 4; j++) {
                s[j][r] = s[j][r] * 0.125f + mb[j];
                tmax = fmaxf(tmax, s[j][r]);
            }
#pragma unroll
            for (int msk = 1; msk < 16; msk <<= 1) tmax = fmaxf(tmax, __shfl_xor(tmax, msk));
            float mn = fmaxf(m_[r], tmax);
            float alpha = __expf(m_[r] - mn);
            float ps = 0.f;
#pragma unroll
            for (int j = 0; j < 4; j++) { p[j][r] = __expf(s[j][r] - mn); ps += p[j][r]; }
#pragma unroll
            for (int msk = 1; msk < 16; msk <<= 1) ps += __shfl_xor(ps, msk);
            l_[r] = l_[r] * alpha + ps;
            m_[r] = mn;
#pragma unroll
            for (int g = 0; g < 4; g++) o[g][r] *= alpha;
        }
        // P -> per-wave LDS (re-fragment for PV's A-operand); same-wave dep, compiler orders lgkmcnt
#pragma unroll
        for (int r = 0; r < 4; r++)
#pragma unroll
            for (int j = 0; j < 4; j++)
                Pl[w][((lane >> 4) * 4 + r) * 72 + j * 16 + (lane & 15)] = f2bf(p[j][r]);

#pragma unroll
        for (int g = 0; g < 4; g++)
#pragma unroll
            for (int half = 0; half < 2; half++) {
                bf16x8 pf = *(bf16x8*)&Pl[w][(lane & 15) * 72 + half * 32 + (lane >> 4) * 8];
                bf16x8 vf = *(bf16x8*)&Vs[(g * 16 + (lane & 15)) * 72 + half * 32 + (lane >> 4) * 8];
                o[g] = __builtin_amdgcn_mfma_f32_16x16x32_bf16(pf, vf, o[g], 0, 0, 0);
            }
    }
#pragma unroll
    for (int g = 0; g < 4; g++)
#pragma unroll
        for (int r = 0; r < 4; r++) {
            int t = q0 + w * 16 + (lane >> 4) * 4 + r;
            int col = h * DKK + g * 16 + (lane & 15);
            float v = o[g][r] / l_[r];
            ctx[((size_t)(b * TT + t)) * HH + col] = f2bf(v);
        }
}

// ---------------- row LayerNorm in-place on d_out (fp32), eps=1e-12 ----------------
__global__ __launch_bounds__(256) void ln_kernel(float* __restrict__ x,
                                                 const float* __restrict__ gam,
                                                 const float* __restrict__ bet) {
    int row = blockIdx.x, tid = threadIdx.x;
    float4 v = reinterpret_cast<float4*>(x)[(size_t)row * 256 + tid];
    float s = v.x + v.y + v.z + v.w;
#pragma unroll
    for (int m = 1; m < 64; m <<= 1) s += __shfl_xor(s, m);
    __shared__ float red[4], red2[4];
    if ((tid & 63) == 0) red[tid >> 6] = s;
    __syncthreads();
    float mean = (red[0] + red[1] + red[2] + red[3]) * (1.f / 1024.f);
    float dx0 = v.x - mean, dx1 = v.y - mean, dx2 = v.z - mean, dx3 = v.w - mean;
    float ss = dx0 * dx0 + dx1 * dx1 + dx2 * dx2 + dx3 * dx3;
#pragma unroll
    for (int m = 1; m < 64; m <<= 1) ss += __shfl_xor(ss, m);
    if ((tid & 63) == 0) red2[tid >> 6] = ss;
    __syncthreads();
    float var = (red2[0] + red2[1] + red2[2] + red2[3]) * (1.f / 1024.f);
    float rs = rsqrtf(var + 1e-12f);
    int c = tid * 4;
    float4 ov;
    ov.x = dx0 * rs * gam[c + 0] + bet[c + 0];
    ov.y = dx1 * rs * gam[c + 1] + bet[c + 1];
    ov.z = dx2 * rs * gam[c + 2] + bet[c + 2];
    ov.w = dx3 * rs * gam[c + 3] + bet[c + 3];
    reinterpret_cast<float4*>(x)[(size_t)row * 256 + tid] = ov;
}

extern "C" void kernel_launch(void* const* d_in, const int* in_sizes, int n_in,
                              void* d_out, int out_size, void* d_ws, size_t ws_size,
                              hipStream_t stream) {
    const float* hid  = (const float*)d_in[0];
    const float* src  = (const float*)d_in[1];
    const int* slen   = (const int*)d_in[2];   // harness passes integers as int32
    const float* Wq  = (const float*)d_in[3];  const float* bq  = (const float*)d_in[4];
    const float* Wk  = (const float*)d_in[5];  const float* bk  = (const float*)d_in[6];
    const float* Wv  = (const float*)d_in[7];  const float* bv  = (const float*)d_in[8];
    const float* Wd  = (const float*)d_in[9];  const float* bd  = (const float*)d_in[10];
    const float* Wp1 = (const float*)d_in[11]; const float* bp1 = (const float*)d_in[12];
    const float* Wp2 = (const float*)d_in[13]; const float* bp2 = (const float*)d_in[14];
    const float* lng = (const float*)d_in[15]; const float* lnb = (const float*)d_in[16];

    // Workspace layout (bytes). Needs 92 MB.
    char* ws = (char*)d_ws;
    const size_t MB = 1ull << 20;
    unsigned short* Wqt  = (unsigned short*)(ws + 0 * MB);
    unsigned short* Wkt  = (unsigned short*)(ws + 2 * MB);
    unsigned short* Wvt  = (unsigned short*)(ws + 4 * MB);
    unsigned short* Wdt  = (unsigned short*)(ws + 6 * MB);
    unsigned short* Wp1t = (unsigned short*)(ws + 8 * MB);
    unsigned short* Wp2t = (unsigned short*)(ws + 10 * MB);
    unsigned short* hidb = (unsigned short*)(ws + 12 * MB);  // later aliased as Kb
    unsigned short* srcb = (unsigned short*)(ws + 28 * MB);  // later aliased as ctx
    unsigned short* Ptmp = (unsigned short*)(ws + 44 * MB);  // later aliased as Vtb
    unsigned short* Pb   = (unsigned short*)(ws + 60 * MB);
    unsigned short* Qb   = (unsigned short*)(ws + 76 * MB);
    unsigned short* Kb   = hidb;
    unsigned short* Vtb  = Ptmp;
    unsigned short* ctxb = srcb;

    dim3 tb(32, 8);
    wtcvt_kernel<<<dim3(32, 32), tb, 0, stream>>>(Wq, Wqt);
    wtcvt_kernel<<<dim3(32, 32), tb, 0, stream>>>(Wk, Wkt);
    wtcvt_kernel<<<dim3(32, 32), tb, 0, stream>>>(Wv, Wvt);
    wtcvt_kernel<<<dim3(32, 32), tb, 0, stream>>>(Wd, Wdt);
    wtcvt_kernel<<<dim3(32, 32), tb, 0, stream>>>(Wp1, Wp1t);
    wtcvt_kernel<<<dim3(32, 32), tb, 0, stream>>>(Wp2, Wp2t);

    const int n4 = (BB * TT * HH) / 4;  // 2M float4s
    cvt_kernel<<<n4 / 256, 256, 0, stream>>>(hid, hidb, n4);
    cvt_kernel<<<n4 / 256, 256, 0, stream>>>(src, srcb, n4);

    dim3 gg(HH / 128, (BB * TT) / 128);  // (8, 64)
    // P = mask(relu(src@Wp1+bp1)@Wp2+bp2)
    gemm_kernel<1><<<gg, 256, 0, stream>>>(srcb, Wp1t, bp1, Ptmp, nullptr, nullptr, nullptr, BB * TT, HH, HH);
    gemm_kernel<2><<<gg, 256, 0, stream>>>(Ptmp, Wp2t, bp2, Pb, nullptr, nullptr, slen, BB * TT, HH, HH);
    // Q,K head-split; V transposed-head
    gemm_kernel<3><<<gg, 256, 0, stream>>>(hidb, Wqt, bq, Qb, nullptr, nullptr, nullptr, BB * TT, HH, HH);
    gemm_kernel<3><<<gg, 256, 0, stream>>>(Pb, Wkt, bk, Kb, nullptr, nullptr, nullptr, BB * TT, HH, HH);
    gemm_kernel<4><<<gg, 256, 0, stream>>>(Pb, Wvt, bv, Vtb, nullptr, nullptr, nullptr, BB * TT, HH, HH);
    // attention -> ctx (B,T,H) bf16
    attn_kernel<<<dim3(TT / 64, NHH, BB), 256, 0, stream>>>(Qb, Kb, Vtb, slen, ctxb);
    // x = ctx@Wd + bd + hidden -> d_out fp32
    gemm_kernel<5><<<gg, 256, 0, stream>>>(ctxb, Wdt, bd, nullptr, (float*)d_out, hid, nullptr, BB * TT, HH, HH);
    // LayerNorm in place
    ln_kernel<<<BB * TT, 256, 0, stream>>>((float*)d_out, lng, lnb);
}

// Round 4
// 339.705 us; speedup vs baseline: 1.5947x; 1.0231x over previous
//
#include <hip/hip_runtime.h>
#include <hip/hip_bf16.h>

// Problem dims (fixed by the reference)
#define BB 4
#define TT 2048
#define HH 1024
#define NHH 16
#define DKK 64
// M = BB*TT = 8192, K = N = HH = 1024

typedef __attribute__((ext_vector_type(8))) short bf16x8;
typedef __attribute__((ext_vector_type(4))) float f32x4;

__device__ __forceinline__ unsigned short f2bf(float f) {
    union { float f; unsigned u; } v; v.f = f;
    unsigned r = v.u + 0x7fffu + ((v.u >> 16) & 1u);  // RNE
    return (unsigned short)(r >> 16);
}

// async global->LDS, 16B per lane; LDS dest must be linear in lane order
__device__ __forceinline__ void gload_lds16(const unsigned short* g, unsigned short* l) {
    __builtin_amdgcn_global_load_lds(
        (const __attribute__((address_space(1))) unsigned int*)g,
        (__attribute__((address_space(3))) unsigned int*)l, 16, 0, 0);
}

__device__ __forceinline__ unsigned lds_off(const void* p) {
    return (unsigned)(unsigned long long)(const __attribute__((address_space(3))) char*)p;
}

// ---------------- fp32 -> bf16 elementwise convert (vector x4) ----------------
__global__ __launch_bounds__(256) void cvt_kernel(const float* __restrict__ in,
                                                  unsigned short* __restrict__ out, int n4) {
    int i = blockIdx.x * blockDim.x + threadIdx.x;
    if (i < n4) {
        float4 v = reinterpret_cast<const float4*>(in)[i];
        union { unsigned short u[4]; unsigned long long ll; } o;
        o.u[0] = f2bf(v.x); o.u[1] = f2bf(v.y); o.u[2] = f2bf(v.z); o.u[3] = f2bf(v.w);
        reinterpret_cast<unsigned long long*>(out)[i] = o.ll;
    }
}

// ---------------- weight transpose + convert: Wt[n][k] = (bf16)W[k][n], 1024x1024 ----------------
__global__ __launch_bounds__(256) void wtcvt_kernel(const float* __restrict__ W,
                                                    unsigned short* __restrict__ Wt) {
    __shared__ float t[32][33];
    int bx = blockIdx.x * 32, by = blockIdx.y * 32;
    int tx = threadIdx.x, ty = threadIdx.y;   // block (32,8)
#pragma unroll
    for (int i = 0; i < 32; i += 8)
        t[ty + i][tx] = W[(size_t)(by + ty + i) * HH + bx + tx];
    __syncthreads();
#pragma unroll
    for (int i = 0; i < 32; i += 8)
        Wt[(size_t)(bx + ty + i) * HH + by + tx] = f2bf(t[tx][ty + i]);
}

// ---------------- MFMA GEMM (m97 structure): 128x128 tile, BK=64, global_load_lds w=16 ----------------
// EPI: 1=relu->bf16  2=source-mask->bf16  3=head-split store (Q/K)  4=transposed-head (V)  5=+resid, fp32 out
// SKIP: early-exit row-tiles whose outputs are never read (rows >= ceil64(source_len) of the P chain)
template <int EPI, bool SKIP>
__global__ __launch_bounds__(256) void gemm_kernel(
    const unsigned short* __restrict__ A, const unsigned short* __restrict__ Bt,
    const float* __restrict__ bias, unsigned short* __restrict__ Cb,
    float* __restrict__ Cf, const float* __restrict__ resid,
    const int* __restrict__ slen, int M, int N, int K) {
    __shared__ unsigned short As[128 * 64];   // [row][k] linear (global_load_lds needs no pad)
    __shared__ unsigned short Bs[128 * 64];
    int by = blockIdx.y * 128, bx = blockIdx.x * 128;
    if constexpr (SKIP) {
        int slb = slen[by >> 11];
        int ktend = ((slb + 63) >> 6) << 6;
        if (ktend == 0) ktend = 64;           // attention still reads tile 0 (uniform-softmax case)
        if ((by & (TT - 1)) >= ktend) return; // whole 128-row tile dead (2048 % 128 == 0)
    }
    int tid = threadIdx.x, lane = tid & 63, w = tid >> 6;
    int wr = (w >> 1) * 64, wc = (w & 1) * 64;     // wave's 64x64 output quadrant

    f32x4 acc[4][4] = {};
    for (int k0 = 0; k0 < K; k0 += 64) {
        __syncthreads();
        // stage 128x64 bf16 A and B tiles: 1024 chunks x 16B each; 4 chunks/thread
#pragma unroll
        for (int c = 0; c < 4; c++) {
            int idx = c * 256 + tid;              // lane-consecutive within each wave
            int r = idx >> 3, col = (idx & 7) * 8;
            gload_lds16(&A[(size_t)(by + r) * K + k0 + col], &As[idx * 8]);
            gload_lds16(&Bt[(size_t)(bx + r) * K + k0 + col], &Bs[idx * 8]);
        }
        __syncthreads();  // compiler drains vmcnt(0) here (global_load_lds complete)
#pragma unroll
        for (int kk = 0; kk < 2; kk++) {
            bf16x8 a[4], b[4];
#pragma unroll
            for (int i = 0; i < 4; i++)
                a[i] = *(bf16x8*)&As[(wr + i * 16 + (lane & 15)) * 64 + kk * 32 + (lane >> 4) * 8];
#pragma unroll
            for (int j = 0; j < 4; j++)
                b[j] = *(bf16x8*)&Bs[(wc + j * 16 + (lane & 15)) * 64 + kk * 32 + (lane >> 4) * 8];
#pragma unroll
            for (int i = 0; i < 4; i++)
#pragma unroll
                for (int j = 0; j < 4; j++)
                    acc[i][j] = __builtin_amdgcn_mfma_f32_16x16x32_bf16(a[i], b[j], acc[i][j], 0, 0, 0);
        }
    }

    int sl = 0;
    if constexpr (EPI == 2) sl = slen[by >> 11];  // 128-row tile never crosses a batch
#pragma unroll
    for (int i = 0; i < 4; i++)
#pragma unroll
        for (int j = 0; j < 4; j++)
#pragma unroll
            for (int r = 0; r < 4; r++) {
                int row = by + wr + i * 16 + (lane >> 4) * 4 + r;
                int col = bx + wc + j * 16 + (lane & 15);
                float v = acc[i][j][r] + bias[col];
                if constexpr (EPI == 1) v = fmaxf(v, 0.f);
                if constexpr (EPI == 2) { int t = row & (TT - 1); if (t >= sl) v = 0.f; }
                if constexpr (EPI == 1 || EPI == 2) {
                    Cb[(size_t)row * N + col] = f2bf(v);
                } else if constexpr (EPI == 3) {
                    int b = row >> 11, t = row & (TT - 1), h = col >> 6, d = col & 63;
                    Cb[((size_t)((b * NHH + h) * TT + t)) * DKK + d] = f2bf(v);
                } else if constexpr (EPI == 4) {
                    int b = row >> 11, t = row & (TT - 1), h = col >> 6, d = col & 63;
                    Cb[((size_t)((b * NHH + h) * DKK + d)) * TT + t] = f2bf(v);
                } else if constexpr (EPI == 5) {
                    Cf[(size_t)row * N + col] = v + resid[(size_t)row * N + col];
                }
            }
}

// ---------------- flash attention: block = (b, h, 64 q-rows), 4 waves x 16 q-rows ----------------
// Skips fully-masked KV tiles (exp(-10000-m)==0 exactly in fp32). P round-trips LDS transposed:
// write P^T[kv][16 q] (stride 16 = tr_read's fixed HW stride) as packed b64; read A-fragments
// back with ds_read_b64_tr_b16 (per-lane addr 2c+256g, elems at +{0,32,64,96}B -> kv+0..3).
__global__ __launch_bounds__(256) void attn_kernel(
    const unsigned short* __restrict__ Q, const unsigned short* __restrict__ K,
    const unsigned short* __restrict__ Vt, const int* __restrict__ slen,
    unsigned short* __restrict__ ctx) {
    __shared__ unsigned short Ks[64 * 72];        // [kv][dk] padded
    __shared__ unsigned short Vs[64 * 72];        // [dk][kv] padded
    __shared__ unsigned short Pt[4][64 * 16];     // per-wave P^T [kv][q], stride 16 (tr layout)
    int tid = threadIdx.x, lane = tid & 63, w = tid >> 6;
    int c = lane & 15, g = lane >> 4;
    int b = blockIdx.z, h = blockIdx.y, q0 = blockIdx.x * 64;
    size_t bh = (size_t)(b * NHH + h);
    int sl = slen[b];
    int ktend = ((sl + 63) >> 6) << 6;
    if (ktend == 0) ktend = 64;                   // all-masked: one tile, uniform softmax -> bv

    bf16x8 qf[2];
    int qrow = q0 + w * 16 + c;
#pragma unroll
    for (int half = 0; half < 2; half++)
        qf[half] = *(const bf16x8*)&Q[(bh * TT + qrow) * DKK + half * 32 + g * 8];

    unsigned pbase = lds_off(&Pt[w][0]);          // LDS byte offset of this wave's P^T
    unsigned ptr_rd = pbase + 2 * c + (g << 8);   // + 1024*half per half, +128 for kv+4

    float m_[4], l_[4];
    f32x4 o[4] = {};
#pragma unroll
    for (int r = 0; r < 4; r++) { m_[r] = -INFINITY; l_[r] = 0.f; }

    for (int kt = 0; kt < ktend; kt += 64) {
        __syncthreads();
#pragma unroll
        for (int cc = 0; cc < 2; cc++) {
            int idx = tid + cc * 256;
            int r = idx >> 3, kc = (idx & 7) * 8;
            *(bf16x8*)&Ks[r * 72 + kc] = *(const bf16x8*)&K[(bh * TT + kt + r) * DKK + kc];
            *(bf16x8*)&Vs[r * 72 + kc] = *(const bf16x8*)&Vt[(bh * DKK + r) * TT + kt + kc];
        }
        __syncthreads();

        f32x4 s[4] = {};
#pragma unroll
        for (int j = 0; j < 4; j++)
#pragma unroll
            for (int half = 0; half < 2; half++) {
                bf16x8 kf = *(bf16x8*)&Ks[(j * 16 + c) * 72 + half * 32 + g * 8];
                s[j] = __builtin_amdgcn_mfma_f32_16x16x32_bf16(qf[half], kf, s[j], 0, 0, 0);
            }

        float mb[4];
#pragma unroll
        for (int j = 0; j < 4; j++) {
            int kvi = kt + j * 16 + c;
            mb[j] = (kvi < sl) ? 0.f : -10000.f;
        }

        float p[4][4];
#pragma unroll
        for (int r = 0; r < 4; r++) {
            float tmax = -INFINITY;
#pragma unroll
            for (int j = 0; j < 4; j++) {
                s[j][r] = s[j][r] * 0.125f + mb[j];
                tmax = fmaxf(tmax, s[j][r]);
            }
#pragma unroll
            for (int msk = 1; msk < 16; msk <<= 1) tmax = fmaxf(tmax, __shfl_xor(tmax, msk));
            float mn = fmaxf(m_[r], tmax);
            float alpha = __expf(m_[r] - mn);
            float ps = 0.f;
#pragma unroll
            for (int j = 0; j < 4; j++) { p[j][r] = __expf(s[j][r] - mn); ps += p[j][r]; }
#pragma unroll
            for (int msk = 1; msk < 16; msk <<= 1) ps += __shfl_xor(ps, msk);
            l_[r] = l_[r] * alpha + ps;
            m_[r] = mn;
#pragma unroll
            for (int g2 = 0; g2 < 4; g2++) o[g2][r] *= alpha;
        }

        // P^T[kv = j*16+c][q = 4g + r]: pack 4 row-values (contiguous q) -> one ds_write_b64
#pragma unroll
        for (int j = 0; j < 4; j++) {
            __hip_bfloat162 lo = __float22bfloat162_rn(make_float2(p[j][0], p[j][1]));
            __hip_bfloat162 hi = __float22bfloat162_rn(make_float2(p[j][2], p[j][3]));
            uint2 u;
            u.x = *(unsigned*)&lo;
            u.y = *(unsigned*)&hi;
            *(uint2*)&Pt[w][((j * 16 + c) << 4) + (g << 2)] = u;
        }

        // read P A-fragments back, transposed: lane gets P[q=c][kv = 32*half + 8g + e]
        unsigned long long t00, t01, t10, t11;
        asm volatile(
            "ds_read_b64_tr_b16 %0, %4 offset:0\n\t"
            "ds_read_b64_tr_b16 %1, %4 offset:128\n\t"
            "ds_read_b64_tr_b16 %2, %5 offset:0\n\t"
            "ds_read_b64_tr_b16 %3, %5 offset:128\n\t"
            "s_waitcnt lgkmcnt(0)"
            : "=&v"(t00), "=&v"(t01), "=&v"(t10), "=&v"(t11)
            : "v"(ptr_rd), "v"(ptr_rd + 1024)
            : "memory");
        __builtin_amdgcn_sched_barrier(0);
        union { unsigned long long q[2]; bf16x8 v; } pf0, pf1;
        pf0.q[0] = t00; pf0.q[1] = t01;
        pf1.q[0] = t10; pf1.q[1] = t11;

#pragma unroll
        for (int go = 0; go < 4; go++) {
            bf16x8 vf0 = *(bf16x8*)&Vs[(go * 16 + c) * 72 + 0 * 32 + g * 8];
            o[go] = __builtin_amdgcn_mfma_f32_16x16x32_bf16(pf0.v, vf0, o[go], 0, 0, 0);
            bf16x8 vf1 = *(bf16x8*)&Vs[(go * 16 + c) * 72 + 1 * 32 + g * 8];
            o[go] = __builtin_amdgcn_mfma_f32_16x16x32_bf16(pf1.v, vf1, o[go], 0, 0, 0);
        }
    }
#pragma unroll
    for (int go = 0; go < 4; go++)
#pragma unroll
        for (int r = 0; r < 4; r++) {
            int t = q0 + w * 16 + g * 4 + r;
            int col = h * DKK + go * 16 + c;
            float v = o[go][r] / l_[r];
            ctx[((size_t)(b * TT + t)) * HH + col] = f2bf(v);
        }
}

// ---------------- row LayerNorm in-place on d_out (fp32), eps=1e-12 ----------------
__global__ __launch_bounds__(256) void ln_kernel(float* __restrict__ x,
                                                 const float* __restrict__ gam,
                                                 const float* __restrict__ bet) {
    int row = blockIdx.x, tid = threadIdx.x;
    float4 v = reinterpret_cast<float4*>(x)[(size_t)row * 256 + tid];
    float s = v.x + v.y + v.z + v.w;
#pragma unroll
    for (int m = 1; m < 64; m <<= 1) s += __shfl_xor(s, m);
    __shared__ float red[4], red2[4];
    if ((tid & 63) == 0) red[tid >> 6] = s;
    __syncthreads();
    float mean = (red[0] + red[1] + red[2] + red[3]) * (1.f / 1024.f);
    float dx0 = v.x - mean, dx1 = v.y - mean, dx2 = v.z - mean, dx3 = v.w - mean;
    float ss = dx0 * dx0 + dx1 * dx1 + dx2 * dx2 + dx3 * dx3;
#pragma unroll
    for (int m = 1; m < 64; m <<= 1) ss += __shfl_xor(ss, m);
    if ((tid & 63) == 0) red2[tid >> 6] = ss;
    __syncthreads();
    float var = (red2[0] + red2[1] + red2[2] + red2[3]) * (1.f / 1024.f);
    float rs = rsqrtf(var + 1e-12f);
    int c = tid * 4;
    float4 ov;
    ov.x = dx0 * rs * gam[c + 0] + bet[c + 0];
    ov.y = dx1 * rs * gam[c + 1] + bet[c + 1];
    ov.z = dx2 * rs * gam[c + 2] + bet[c + 2];
    ov.w = dx3 * rs * gam[c + 3] + bet[c + 3];
    reinterpret_cast<float4*>(x)[(size_t)row * 256 + tid] = ov;
}

extern "C" void kernel_launch(void* const* d_in, const int* in_sizes, int n_in,
                              void* d_out, int out_size, void* d_ws, size_t ws_size,
                              hipStream_t stream) {
    const float* hid  = (const float*)d_in[0];
    const float* src  = (const float*)d_in[1];
    const int* slen   = (const int*)d_in[2];   // harness passes integers as int32
    const float* Wq  = (const float*)d_in[3];  const float* bq  = (const float*)d_in[4];
    const float* Wk  = (const float*)d_in[5];  const float* bk  = (const float*)d_in[6];
    const float* Wv  = (const float*)d_in[7];  const float* bv  = (const float*)d_in[8];
    const float* Wd  = (const float*)d_in[9];  const float* bd  = (const float*)d_in[10];
    const float* Wp1 = (const float*)d_in[11]; const float* bp1 = (const float*)d_in[12];
    const float* Wp2 = (const float*)d_in[13]; const float* bp2 = (const float*)d_in[14];
    const float* lng = (const float*)d_in[15]; const float* lnb = (const float*)d_in[16];

    // Workspace layout (bytes). Needs 92 MB.
    char* ws = (char*)d_ws;
    const size_t MB = 1ull << 20;
    unsigned short* Wqt  = (unsigned short*)(ws + 0 * MB);
    unsigned short* Wkt  = (unsigned short*)(ws + 2 * MB);
    unsigned short* Wvt  = (unsigned short*)(ws + 4 * MB);
    unsigned short* Wdt  = (unsigned short*)(ws + 6 * MB);
    unsigned short* Wp1t = (unsigned short*)(ws + 8 * MB);
    unsigned short* Wp2t = (unsigned short*)(ws + 10 * MB);
    unsigned short* hidb = (unsigned short*)(ws + 12 * MB);  // later aliased as Kb
    unsigned short* srcb = (unsigned short*)(ws + 28 * MB);  // later aliased as ctx
    unsigned short* Ptmp = (unsigned short*)(ws + 44 * MB);  // later aliased as Vtb
    unsigned short* Pb   = (unsigned short*)(ws + 60 * MB);
    unsigned short* Qb   = (unsigned short*)(ws + 76 * MB);
    unsigned short* Kb   = hidb;
    unsigned short* Vtb  = Ptmp;
    unsigned short* ctxb = srcb;

    dim3 tb(32, 8);
    wtcvt_kernel<<<dim3(32, 32), tb, 0, stream>>>(Wq, Wqt);
    wtcvt_kernel<<<dim3(32, 32), tb, 0, stream>>>(Wk, Wkt);
    wtcvt_kernel<<<dim3(32, 32), tb, 0, stream>>>(Wv, Wvt);
    wtcvt_kernel<<<dim3(32, 32), tb, 0, stream>>>(Wd, Wdt);
    wtcvt_kernel<<<dim3(32, 32), tb, 0, stream>>>(Wp1, Wp1t);
    wtcvt_kernel<<<dim3(32, 32), tb, 0, stream>>>(Wp2, Wp2t);

    const int n4 = (BB * TT * HH) / 4;  // 2M float4s
    cvt_kernel<<<n4 / 256, 256, 0, stream>>>(hid, hidb, n4);
    cvt_kernel<<<n4 / 256, 256, 0, stream>>>(src, srcb, n4);

    dim3 gg(HH / 128, (BB * TT) / 128);  // (8, 64)
    // P = mask(relu(src@Wp1+bp1)@Wp2+bp2); rows >= ceil64(sl) are dead -> SKIP
    gemm_kernel<1, true><<<gg, 256, 0, stream>>>(srcb, Wp1t, bp1, Ptmp, nullptr, nullptr, slen, BB * TT, HH, HH);
    gemm_kernel<2, true><<<gg, 256, 0, stream>>>(Ptmp, Wp2t, bp2, Pb, nullptr, nullptr, slen, BB * TT, HH, HH);
    // Q all rows; K,V head-split only live rows
    gemm_kernel<3, false><<<gg, 256, 0, stream>>>(hidb, Wqt, bq, Qb, nullptr, nullptr, slen, BB * TT, HH, HH);
    gemm_kernel<3, true><<<gg, 256, 0, stream>>>(Pb, Wkt, bk, Kb, nullptr, nullptr, slen, BB * TT, HH, HH);
    gemm_kernel<4, true><<<gg, 256, 0, stream>>>(Pb, Wvt, bv, Vtb, nullptr, nullptr, slen, BB * TT, HH, HH);
    // attention -> ctx (B,T,H) bf16
    attn_kernel<<<dim3(TT / 64, NHH, BB), 256, 0, stream>>>(Qb, Kb, Vtb, slen, ctxb);
    // x = ctx@Wd + bd + hidden -> d_out fp32
    gemm_kernel<5, false><<<gg, 256, 0, stream>>>(ctxb, Wdt, bd, nullptr, (float*)d_out, hid, slen, BB * TT, HH, HH);
    // LayerNorm in place
    ln_kernel<<<BB * TT, 256, 0, stream>>>((float*)d_out, lng, lnb);
}

// Round 5
// 305.346 us; speedup vs baseline: 1.7742x; 1.1125x over previous
//
#include <hip/hip_runtime.h>
#include <hip/hip_bf16.h>

// Problem dims (fixed by the reference)
#define BB 4
#define TT 2048
#define HH 1024
#define NHH 16
#define DKK 64
// M = BB*TT = 8192, K = N = HH = 1024

typedef __attribute__((ext_vector_type(8))) short bf16x8;
typedef __attribute__((ext_vector_type(4))) float f32x4;

__device__ __forceinline__ unsigned short f2bf(float f) {
    union { float f; unsigned u; } v; v.f = f;
    unsigned r = v.u + 0x7fffu + ((v.u >> 16) & 1u);  // RNE
    return (unsigned short)(r >> 16);
}

// async global->LDS, 16B per lane; LDS dest must be linear in lane order
__device__ __forceinline__ void gload_lds16(const unsigned short* g, unsigned short* l) {
    __builtin_amdgcn_global_load_lds(
        (const __attribute__((address_space(1))) unsigned int*)g,
        (__attribute__((address_space(3))) unsigned int*)l, 16, 0, 0);
}

// ---------------- fp32 -> bf16 elementwise convert (vector x4) ----------------
__global__ __launch_bounds__(256) void cvt_kernel(const float* __restrict__ in,
                                                  unsigned short* __restrict__ out, int n4) {
    int i = blockIdx.x * blockDim.x + threadIdx.x;
    if (i < n4) {
        float4 v = reinterpret_cast<const float4*>(in)[i];
        union { unsigned short u[4]; unsigned long long ll; } o;
        o.u[0] = f2bf(v.x); o.u[1] = f2bf(v.y); o.u[2] = f2bf(v.z); o.u[3] = f2bf(v.w);
        reinterpret_cast<unsigned long long*>(out)[i] = o.ll;
    }
}

// ---------------- weight transpose + convert: Wt[n][k] = (bf16)W[k][n], 1024x1024 ----------------
__global__ __launch_bounds__(256) void wtcvt_kernel(const float* __restrict__ W,
                                                    unsigned short* __restrict__ Wt) {
    __shared__ float t[32][33];
    int bx = blockIdx.x * 32, by = blockIdx.y * 32;
    int tx = threadIdx.x, ty = threadIdx.y;   // block (32,8)
#pragma unroll
    for (int i = 0; i < 32; i += 8)
        t[ty + i][tx] = W[(size_t)(by + ty + i) * HH + bx + tx];
    __syncthreads();
#pragma unroll
    for (int i = 0; i < 32; i += 8)
        Wt[(size_t)(bx + ty + i) * HH + by + tx] = f2bf(t[tx][ty + i]);
}

// ---------------- MFMA GEMM (m97 structure): 128x128 tile, BK=64, global_load_lds w=16 ----------------
// EPI: 1=relu->bf16  2=source-mask->bf16  3=head-split store (Q/K)  4=transposed-head (V)  5=+resid, fp32 out
// SKIP kept (harmless; grid is one block-wave so it buys little wall time)
template <int EPI, bool SKIP>
__global__ __launch_bounds__(256) void gemm_kernel(
    const unsigned short* __restrict__ A, const unsigned short* __restrict__ Bt,
    const float* __restrict__ bias, unsigned short* __restrict__ Cb,
    float* __restrict__ Cf, const float* __restrict__ resid,
    const int* __restrict__ slen, int M, int N, int K) {
    __shared__ unsigned short As[128 * 64];   // [row][k] linear (global_load_lds needs no pad)
    __shared__ unsigned short Bs[128 * 64];
    int by = blockIdx.y * 128, bx = blockIdx.x * 128;
    if constexpr (SKIP) {
        int slb = slen[by >> 11];
        int ktend = ((slb + 63) >> 6) << 6;
        if (ktend == 0) ktend = 64;           // attention still reads tile 0 (uniform-softmax case)
        if ((by & (TT - 1)) >= ktend) return; // whole 128-row tile dead (2048 % 128 == 0)
    }
    int tid = threadIdx.x, lane = tid & 63, w = tid >> 6;
    int wr = (w >> 1) * 64, wc = (w & 1) * 64;     // wave's 64x64 output quadrant

    f32x4 acc[4][4] = {};
    for (int k0 = 0; k0 < K; k0 += 64) {
        __syncthreads();
        // stage 128x64 bf16 A and B tiles: 1024 chunks x 16B each; 4 chunks/thread
#pragma unroll
        for (int c = 0; c < 4; c++) {
            int idx = c * 256 + tid;              // lane-consecutive within each wave
            int r = idx >> 3, col = (idx & 7) * 8;
            gload_lds16(&A[(size_t)(by + r) * K + k0 + col], &As[idx * 8]);
            gload_lds16(&Bt[(size_t)(bx + r) * K + k0 + col], &Bs[idx * 8]);
        }
        __syncthreads();  // compiler drains vmcnt(0) here (global_load_lds complete)
#pragma unroll
        for (int kk = 0; kk < 2; kk++) {
            bf16x8 a[4], b[4];
#pragma unroll
            for (int i = 0; i < 4; i++)
                a[i] = *(bf16x8*)&As[(wr + i * 16 + (lane & 15)) * 64 + kk * 32 + (lane >> 4) * 8];
#pragma unroll
            for (int j = 0; j < 4; j++)
                b[j] = *(bf16x8*)&Bs[(wc + j * 16 + (lane & 15)) * 64 + kk * 32 + (lane >> 4) * 8];
#pragma unroll
            for (int i = 0; i < 4; i++)
#pragma unroll
                for (int j = 0; j < 4; j++)
                    acc[i][j] = __builtin_amdgcn_mfma_f32_16x16x32_bf16(a[i], b[j], acc[i][j], 0, 0, 0);
        }
    }

    int sl = 0;
    if constexpr (EPI == 2) sl = slen[by >> 11];  // 128-row tile never crosses a batch
#pragma unroll
    for (int i = 0; i < 4; i++)
#pragma unroll
        for (int j = 0; j < 4; j++)
#pragma unroll
            for (int r = 0; r < 4; r++) {
                int row = by + wr + i * 16 + (lane >> 4) * 4 + r;
                int col = bx + wc + j * 16 + (lane & 15);
                float v = acc[i][j][r] + bias[col];
                if constexpr (EPI == 1) v = fmaxf(v, 0.f);
                if constexpr (EPI == 2) { int t = row & (TT - 1); if (t >= sl) v = 0.f; }
                if constexpr (EPI == 1 || EPI == 2) {
                    Cb[(size_t)row * N + col] = f2bf(v);
                } else if constexpr (EPI == 3) {
                    int b = row >> 11, t = row & (TT - 1), h = col >> 6, d = col & 63;
                    Cb[((size_t)((b * NHH + h) * TT + t)) * DKK + d] = f2bf(v);
                } else if constexpr (EPI == 4) {
                    int b = row >> 11, t = row & (TT - 1), h = col >> 6, d = col & 63;
                    Cb[((size_t)((b * NHH + h) * DKK + d)) * TT + t] = f2bf(v);
                } else if constexpr (EPI == 5) {
                    Cf[(size_t)row * N + col] = v + resid[(size_t)row * N + col];
                }
            }
}

// ---------------- flash attention: block = (b, h, 64 q-rows), 4 waves x 16 q-rows ----------------
// SWAPPED QK^T: s = mfma(K, Q) -> D[row=kv][col=q], so each lane owns ONE q-row (q = lane&15)
// with 16 kv values -> softmax reduce = serial ops + 2 shfl_xor (16,32) across the 4 g-lanes.
// P round-trips per-wave LDS [q][kv] with XOR swizzle (byte ^= (q&7)<<4): 4x ds_write_b64 +
// 2x ds_read_b128 per tile, ~2-way conflicts (free). Fully-masked KV tiles skipped (exp==0 in fp32).
__global__ __launch_bounds__(256) void attn_kernel(
    const unsigned short* __restrict__ Q, const unsigned short* __restrict__ K,
    const unsigned short* __restrict__ Vt, const int* __restrict__ slen,
    unsigned short* __restrict__ ctx) {
    __shared__ unsigned short Ks[64 * 72];        // [kv][dk] padded
    __shared__ unsigned short Vs[64 * 72];        // [dk][kv] padded
    __shared__ unsigned short Pl[4][16 * 64];     // per-wave P [q][kv], XOR-swizzled, 2KB/wave
    int tid = threadIdx.x, lane = tid & 63, w = tid >> 6;
    int c = lane & 15, g = lane >> 4;
    int b = blockIdx.z, h = blockIdx.y, q0 = blockIdx.x * 64;
    size_t bh = (size_t)(b * NHH + h);
    int sl = slen[b];
    int ktend = ((sl + 63) >> 6) << 6;
    if (ktend == 0) ktend = 64;                   // all-masked: one tile, uniform softmax -> bv

    bf16x8 qf[2];                                 // B-operand fragment: Q[q=c][dk chunk]
    int qrow = q0 + w * 16 + c;
#pragma unroll
    for (int half = 0; half < 2; half++)
        qf[half] = *(const bf16x8*)&Q[(bh * TT + qrow) * DKK + half * 32 + g * 8];

    char* Pw = (char*)&Pl[w][0];
    unsigned swz = (unsigned)((c & 7) << 4);

    float m_ = -INFINITY, l_ = 0.f;               // online-softmax state for q = c
    f32x4 o[4] = {};                              // O[q = g*4+r][d = go*16+c]

    for (int kt = 0; kt < ktend; kt += 64) {
        __syncthreads();
#pragma unroll
        for (int cc = 0; cc < 2; cc++) {
            int idx = tid + cc * 256;
            int r = idx >> 3, kc = (idx & 7) * 8;
            *(bf16x8*)&Ks[r * 72 + kc] = *(const bf16x8*)&K[(bh * TT + kt + r) * DKK + kc];
            *(bf16x8*)&Vs[r * 72 + kc] = *(const bf16x8*)&Vt[(bh * DKK + r) * TT + kt + kc];
        }
        __syncthreads();

        f32x4 s[4] = {};
        __builtin_amdgcn_s_setprio(1);
#pragma unroll
        for (int j = 0; j < 4; j++)
#pragma unroll
            for (int half = 0; half < 2; half++) {
                bf16x8 kf = *(bf16x8*)&Ks[(j * 16 + c) * 72 + half * 32 + g * 8];
                s[j] = __builtin_amdgcn_mfma_f32_16x16x32_bf16(kf, qf[half], s[j], 0, 0, 0);
            }
        __builtin_amdgcn_s_setprio(0);
        // s[j][r] = S[kv = kt + j*16 + g*4 + r][q = c]

        float sv[4][4];
#pragma unroll
        for (int j = 0; j < 4; j++) {
            int kbase = kt + j * 16 + g * 4;
#pragma unroll
            for (int r = 0; r < 4; r++)
                sv[j][r] = s[j][r] * 0.125f + ((kbase + r < sl) ? 0.f : -10000.f);
        }
        float tmax = -INFINITY;
#pragma unroll
        for (int j = 0; j < 4; j++)
#pragma unroll
            for (int r = 0; r < 4; r++) tmax = fmaxf(tmax, sv[j][r]);
        tmax = fmaxf(tmax, __shfl_xor(tmax, 16));
        tmax = fmaxf(tmax, __shfl_xor(tmax, 32));

        float mn = fmaxf(m_, tmax);
        float alpha = __expf(m_ - mn);
        float ps = 0.f;
#pragma unroll
        for (int j = 0; j < 4; j++)
#pragma unroll
            for (int r = 0; r < 4; r++) {
                float p = __expf(sv[j][r] - mn);
                sv[j][r] = p;
                ps += p;
            }
        ps += __shfl_xor(ps, 16);
        ps += __shfl_xor(ps, 32);
        l_ = l_ * alpha + ps;
        m_ = mn;

        // rescale O: lane's o-rows are q = g*4+r; alpha for that q lives at lane (g*4+r)
        float av[4];
#pragma unroll
        for (int r = 0; r < 4; r++) av[r] = __shfl(alpha, g * 4 + r);
#pragma unroll
        for (int go = 0; go < 4; go++)
#pragma unroll
            for (int r = 0; r < 4; r++) o[go][r] *= av[r];

        // write P[q=c][kv = j*16+g*4 .. +3] (r-contiguous) as one b64, XOR-swizzled
#pragma unroll
        for (int j = 0; j < 4; j++) {
            __hip_bfloat162 lo = __float22bfloat162_rn(make_float2(sv[j][0], sv[j][1]));
            __hip_bfloat162 hi = __float22bfloat162_rn(make_float2(sv[j][2], sv[j][3]));
            uint2 u;
            u.x = *(unsigned*)&lo;
            u.y = *(unsigned*)&hi;
            *(uint2*)(Pw + c * 128 + (((unsigned)(j * 32 + g * 8)) ^ swz)) = u;
        }
        // read A-fragments: P[q=c][kv = half*32 + g*8 .. +7], same swizzle (same-wave dep)
        bf16x8 pf0 = *(bf16x8*)(Pw + c * 128 + (((unsigned)(g * 16)) ^ swz));
        bf16x8 pf1 = *(bf16x8*)(Pw + c * 128 + (((unsigned)(64 + g * 16)) ^ swz));

        __builtin_amdgcn_s_setprio(1);
#pragma unroll
        for (int go = 0; go < 4; go++) {
            bf16x8 vf0 = *(bf16x8*)&Vs[(go * 16 + c) * 72 + g * 8];
            o[go] = __builtin_amdgcn_mfma_f32_16x16x32_bf16(pf0, vf0, o[go], 0, 0, 0);
            bf16x8 vf1 = *(bf16x8*)&Vs[(go * 16 + c) * 72 + 32 + g * 8];
            o[go] = __builtin_amdgcn_mfma_f32_16x16x32_bf16(pf1, vf1, o[go], 0, 0, 0);
        }
        __builtin_amdgcn_s_setprio(0);
    }

    // final divide: l for q = g*4+r lives at lane (g*4+r)
    float linv[4];
#pragma unroll
    for (int r = 0; r < 4; r++) linv[r] = 1.f / __shfl(l_, g * 4 + r);
#pragma unroll
    for (int go = 0; go < 4; go++)
#pragma unroll
        for (int r = 0; r < 4; r++) {
            int t = q0 + w * 16 + g * 4 + r;
            int col = h * DKK + go * 16 + c;
            ctx[((size_t)(b * TT + t)) * HH + col] = f2bf(o[go][r] * linv[r]);
        }
}

// ---------------- row LayerNorm in-place on d_out (fp32), eps=1e-12 ----------------
__global__ __launch_bounds__(256) void ln_kernel(float* __restrict__ x,
                                                 const float* __restrict__ gam,
                                                 const float* __restrict__ bet) {
    int row = blockIdx.x, tid = threadIdx.x;
    float4 v = reinterpret_cast<float4*>(x)[(size_t)row * 256 + tid];
    float s = v.x + v.y + v.z + v.w;
#pragma unroll
    for (int m = 1; m < 64; m <<= 1) s += __shfl_xor(s, m);
    __shared__ float red[4], red2[4];
    if ((tid & 63) == 0) red[tid >> 6] = s;
    __syncthreads();
    float mean = (red[0] + red[1] + red[2] + red[3]) * (1.f / 1024.f);
    float dx0 = v.x - mean, dx1 = v.y - mean, dx2 = v.z - mean, dx3 = v.w - mean;
    float ss = dx0 * dx0 + dx1 * dx1 + dx2 * dx2 + dx3 * dx3;
#pragma unroll
    for (int m = 1; m < 64; m <<= 1) ss += __shfl_xor(ss, m);
    if ((tid & 63) == 0) red2[tid >> 6] = ss;
    __syncthreads();
    float var = (red2[0] + red2[1] + red2[2] + red2[3]) * (1.f / 1024.f);
    float rs = rsqrtf(var + 1e-12f);
    int c = tid * 4;
    float4 ov;
    ov.x = dx0 * rs * gam[c + 0] + bet[c + 0];
    ov.y = dx1 * rs * gam[c + 1] + bet[c + 1];
    ov.z = dx2 * rs * gam[c + 2] + bet[c + 2];
    ov.w = dx3 * rs * gam[c + 3] + bet[c + 3];
    reinterpret_cast<float4*>(x)[(size_t)row * 256 + tid] = ov;
}

extern "C" void kernel_launch(void* const* d_in, const int* in_sizes, int n_in,
                              void* d_out, int out_size, void* d_ws, size_t ws_size,
                              hipStream_t stream) {
    const float* hid  = (const float*)d_in[0];
    const float* src  = (const float*)d_in[1];
    const int* slen   = (const int*)d_in[2];   // harness passes integers as int32
    const float* Wq  = (const float*)d_in[3];  const float* bq  = (const float*)d_in[4];
    const float* Wk  = (const float*)d_in[5];  const float* bk  = (const float*)d_in[6];
    const float* Wv  = (const float*)d_in[7];  const float* bv  = (const float*)d_in[8];
    const float* Wd  = (const float*)d_in[9];  const float* bd  = (const float*)d_in[10];
    const float* Wp1 = (const float*)d_in[11]; const float* bp1 = (const float*)d_in[12];
    const float* Wp2 = (const float*)d_in[13]; const float* bp2 = (const float*)d_in[14];
    const float* lng = (const float*)d_in[15]; const float* lnb = (const float*)d_in[16];

    // Workspace layout (bytes). Needs 92 MB.
    char* ws = (char*)d_ws;
    const size_t MB = 1ull << 20;
    unsigned short* Wqt  = (unsigned short*)(ws + 0 * MB);
    unsigned short* Wkt  = (unsigned short*)(ws + 2 * MB);
    unsigned short* Wvt  = (unsigned short*)(ws + 4 * MB);
    unsigned short* Wdt  = (unsigned short*)(ws + 6 * MB);
    unsigned short* Wp1t = (unsigned short*)(ws + 8 * MB);
    unsigned short* Wp2t = (unsigned short*)(ws + 10 * MB);
    unsigned short* hidb = (unsigned short*)(ws + 12 * MB);  // later aliased as Kb
    unsigned short* srcb = (unsigned short*)(ws + 28 * MB);  // later aliased as ctx
    unsigned short* Ptmp = (unsigned short*)(ws + 44 * MB);  // later aliased as Vtb
    unsigned short* Pb   = (unsigned short*)(ws + 60 * MB);
    unsigned short* Qb   = (unsigned short*)(ws + 76 * MB);
    unsigned short* Kb   = hidb;
    unsigned short* Vtb  = Ptmp;
    unsigned short* ctxb = srcb;

    dim3 tb(32, 8);
    wtcvt_kernel<<<dim3(32, 32), tb, 0, stream>>>(Wq, Wqt);
    wtcvt_kernel<<<dim3(32, 32), tb, 0, stream>>>(Wk, Wkt);
    wtcvt_kernel<<<dim3(32, 32), tb, 0, stream>>>(Wv, Wvt);
    wtcvt_kernel<<<dim3(32, 32), tb, 0, stream>>>(Wd, Wdt);
    wtcvt_kernel<<<dim3(32, 32), tb, 0, stream>>>(Wp1, Wp1t);
    wtcvt_kernel<<<dim3(32, 32), tb, 0, stream>>>(Wp2, Wp2t);

    const int n4 = (BB * TT * HH) / 4;  // 2M float4s
    cvt_kernel<<<n4 / 256, 256, 0, stream>>>(hid, hidb, n4);
    cvt_kernel<<<n4 / 256, 256, 0, stream>>>(src, srcb, n4);

    dim3 gg(HH / 128, (BB * TT) / 128);  // (8, 64)
    // P = mask(relu(src@Wp1+bp1)@Wp2+bp2); rows >= ceil64(sl) are dead -> SKIP
    gemm_kernel<1, true><<<gg, 256, 0, stream>>>(srcb, Wp1t, bp1, Ptmp, nullptr, nullptr, slen, BB * TT, HH, HH);
    gemm_kernel<2, true><<<gg, 256, 0, stream>>>(Ptmp, Wp2t, bp2, Pb, nullptr, nullptr, slen, BB * TT, HH, HH);
    // Q all rows; K,V head-split only live rows
    gemm_kernel<3, false><<<gg, 256, 0, stream>>>(hidb, Wqt, bq, Qb, nullptr, nullptr, slen, BB * TT, HH, HH);
    gemm_kernel<3, true><<<gg, 256, 0, stream>>>(Pb, Wkt, bk, Kb, nullptr, nullptr, slen, BB * TT, HH, HH);
    gemm_kernel<4, true><<<gg, 256, 0, stream>>>(Pb, Wvt, bv, Vtb, nullptr, nullptr, slen, BB * TT, HH, HH);
    // attention -> ctx (B,T,H) bf16
    attn_kernel<<<dim3(TT / 64, NHH, BB), 256, 0, stream>>>(Qb, Kb, Vtb, slen, ctxb);
    // x = ctx@Wd + bd + hidden -> d_out fp32
    gemm_kernel<5, false><<<gg, 256, 0, stream>>>(ctxb, Wdt, bd, nullptr, (float*)d_out, hid, slen, BB * TT, HH, HH);
    // LayerNorm in place
    ln_kernel<<<BB * TT, 256, 0, stream>>>((float*)d_out, lng, lnb);
}

// Round 6
// 286.081 us; speedup vs baseline: 1.8937x; 1.0673x over previous
//
#include <hip/hip_runtime.h>
#include <hip/hip_bf16.h>

// Problem dims (fixed by the reference)
#define BB 4
#define TT 2048
#define HH 1024
#define NHH 16
#define DKK 64
// M = BB*TT = 8192, K = N = HH = 1024

typedef __attribute__((ext_vector_type(8))) short bf16x8;
typedef __attribute__((ext_vector_type(4))) float f32x4;

__device__ __forceinline__ unsigned short f2bf(float f) {
    union { float f; unsigned u; } v; v.f = f;
    unsigned r = v.u + 0x7fffu + ((v.u >> 16) & 1u);  // RNE
    return (unsigned short)(r >> 16);
}

// async global->LDS, 16B per lane; LDS dest must be linear in lane order
__device__ __forceinline__ void gload_lds16(const unsigned short* g, unsigned short* l) {
    __builtin_amdgcn_global_load_lds(
        (const __attribute__((address_space(1))) unsigned int*)g,
        (__attribute__((address_space(3))) unsigned int*)l, 16, 0, 0);
}

// ---------------- fp32 -> bf16 elementwise convert (vector x4) ----------------
__global__ __launch_bounds__(256) void cvt_kernel(const float* __restrict__ in,
                                                  unsigned short* __restrict__ out, int n4) {
    int i = blockIdx.x * blockDim.x + threadIdx.x;
    if (i < n4) {
        float4 v = reinterpret_cast<const float4*>(in)[i];
        union { unsigned short u[4]; unsigned long long ll; } o;
        o.u[0] = f2bf(v.x); o.u[1] = f2bf(v.y); o.u[2] = f2bf(v.z); o.u[3] = f2bf(v.w);
        reinterpret_cast<unsigned long long*>(out)[i] = o.ll;
    }
}

// ---------------- weight transpose + convert: Wt[n][k] = (bf16)W[k][n], 1024x1024 ----------------
__global__ __launch_bounds__(256) void wtcvt_kernel(const float* __restrict__ W,
                                                    unsigned short* __restrict__ Wt) {
    __shared__ float t[32][33];
    int bx = blockIdx.x * 32, by = blockIdx.y * 32;
    int tx = threadIdx.x, ty = threadIdx.y;   // block (32,8)
#pragma unroll
    for (int i = 0; i < 32; i += 8)
        t[ty + i][tx] = W[(size_t)(by + ty + i) * HH + bx + tx];
    __syncthreads();
#pragma unroll
    for (int i = 0; i < 32; i += 8)
        Wt[(size_t)(bx + ty + i) * HH + by + tx] = f2bf(t[tx][ty + i]);
}

// ---------------- MFMA GEMM (m97 structure): 128x128 tile, BK=64, global_load_lds w=16 ----------------
// EPI: 1=relu->bf16  2=source-mask->bf16  3=head-split (K)  4=transposed-head (V)
//      5=+resid fp32 out  6=head-split * 0.125*log2e (Q, feeds base-2 softmax)
template <int EPI, bool SKIP>
__global__ __launch_bounds__(256) void gemm_kernel(
    const unsigned short* __restrict__ A, const unsigned short* __restrict__ Bt,
    const float* __restrict__ bias, unsigned short* __restrict__ Cb,
    float* __restrict__ Cf, const float* __restrict__ resid,
    const int* __restrict__ slen, int M, int N, int K) {
    __shared__ unsigned short As[128 * 64];   // [row][k] linear (global_load_lds needs no pad)
    __shared__ unsigned short Bs[128 * 64];
    int by = blockIdx.y * 128, bx = blockIdx.x * 128;
    if constexpr (SKIP) {
        int slb = slen[by >> 11];
        int ktend = ((slb + 63) >> 6) << 6;
        if (ktend == 0) ktend = 64;           // attention still reads tile 0 (uniform-softmax case)
        if ((by & (TT - 1)) >= ktend) return; // whole 128-row tile dead (2048 % 128 == 0)
    }
    int tid = threadIdx.x, lane = tid & 63, w = tid >> 6;
    int wr = (w >> 1) * 64, wc = (w & 1) * 64;     // wave's 64x64 output quadrant

    f32x4 acc[4][4] = {};
    for (int k0 = 0; k0 < K; k0 += 64) {
        __syncthreads();
        // stage 128x64 bf16 A and B tiles: 1024 chunks x 16B each; 4 chunks/thread
#pragma unroll
        for (int c = 0; c < 4; c++) {
            int idx = c * 256 + tid;              // lane-consecutive within each wave
            int r = idx >> 3, col = (idx & 7) * 8;
            gload_lds16(&A[(size_t)(by + r) * K + k0 + col], &As[idx * 8]);
            gload_lds16(&Bt[(size_t)(bx + r) * K + k0 + col], &Bs[idx * 8]);
        }
        __syncthreads();  // compiler drains vmcnt(0) here (global_load_lds complete)
#pragma unroll
        for (int kk = 0; kk < 2; kk++) {
            bf16x8 a[4], b[4];
#pragma unroll
            for (int i = 0; i < 4; i++)
                a[i] = *(bf16x8*)&As[(wr + i * 16 + (lane & 15)) * 64 + kk * 32 + (lane >> 4) * 8];
#pragma unroll
            for (int j = 0; j < 4; j++)
                b[j] = *(bf16x8*)&Bs[(wc + j * 16 + (lane & 15)) * 64 + kk * 32 + (lane >> 4) * 8];
#pragma unroll
            for (int i = 0; i < 4; i++)
#pragma unroll
                for (int j = 0; j < 4; j++)
                    acc[i][j] = __builtin_amdgcn_mfma_f32_16x16x32_bf16(a[i], b[j], acc[i][j], 0, 0, 0);
        }
    }

    int sl = 0;
    if constexpr (EPI == 2) sl = slen[by >> 11];  // 128-row tile never crosses a batch
#pragma unroll
    for (int i = 0; i < 4; i++)
#pragma unroll
        for (int j = 0; j < 4; j++)
#pragma unroll
            for (int r = 0; r < 4; r++) {
                int row = by + wr + i * 16 + (lane >> 4) * 4 + r;
                int col = bx + wc + j * 16 + (lane & 15);
                float v = acc[i][j][r] + bias[col];
                if constexpr (EPI == 1) v = fmaxf(v, 0.f);
                if constexpr (EPI == 2) { int t = row & (TT - 1); if (t >= sl) v = 0.f; }
                if constexpr (EPI == 6) v *= 0.18033688f;   // 0.125 * log2(e)
                if constexpr (EPI == 1 || EPI == 2) {
                    Cb[(size_t)row * N + col] = f2bf(v);
                } else if constexpr (EPI == 3 || EPI == 6) {
                    int b = row >> 11, t = row & (TT - 1), h = col >> 6, d = col & 63;
                    Cb[((size_t)((b * NHH + h) * TT + t)) * DKK + d] = f2bf(v);
                } else if constexpr (EPI == 4) {
                    int b = row >> 11, t = row & (TT - 1), h = col >> 6, d = col & 63;
                    Cb[((size_t)((b * NHH + h) * DKK + d)) * TT + t] = f2bf(v);
                } else if constexpr (EPI == 5) {
                    Cf[(size_t)row * N + col] = v + resid[(size_t)row * N + col];
                }
            }
}

// ---------------- flash attention: block = (b, h, 128 q-rows), 8 waves x 16 q-rows ----------------
// Swapped QK^T (lane owns one q-row), base-2 softmax (Q pre-scaled by 0.125*log2e in its GEMM),
// full-tile mask skip, T13 defer-max (skip O-rescale when __all(tmax <= m+8); p bounded by 2^8),
// K/V staged via global_load_lds with pre-swizzled source + XOR-swizzled reads (2-way = free).
__global__ __launch_bounds__(512) void attn_kernel(
    const unsigned short* __restrict__ Q, const unsigned short* __restrict__ K,
    const unsigned short* __restrict__ Vt, const int* __restrict__ slen,
    unsigned short* __restrict__ ctx) {
    __shared__ unsigned short Ks[64 * 64];        // [kv][dk], XOR-swizzled content
    __shared__ unsigned short Vs[64 * 64];        // [dk][kv], XOR-swizzled content
    __shared__ unsigned short Pl[8][16 * 64];     // per-wave P [q][kv], XOR-swizzled
    int tid = threadIdx.x, lane = tid & 63, w = tid >> 6;
    int c = lane & 15, g = lane >> 4;
    int b = blockIdx.z, h = blockIdx.y, q0 = blockIdx.x * 128;
    size_t bh = (size_t)(b * NHH + h);
    int sl = slen[b];
    int ktend = ((sl + 63) >> 6) << 6;
    if (ktend == 0) ktend = 64;                   // all-masked: one tile, uniform softmax -> bv

    bf16x8 qf[2];                                 // B-operand: Q[q = w*16+c][dk]
    int qrow = q0 + w * 16 + c;
#pragma unroll
    for (int half = 0; half < 2; half++)
        qf[half] = *(const bf16x8*)&Q[(bh * TT + qrow) * DKK + half * 32 + g * 8];

    char* Pw = (char*)&Pl[w][0];
    unsigned swz = (unsigned)((c & 7) << 4);

    // staging coords: thread stages chunk (r = tid>>3, slot = tid&7) of both K and V;
    // source slot pre-swizzled so LDS[r][s] = G[r][s ^ (r&7)]
    int sr = tid >> 3, ss = tid & 7;
    int scol = (ss ^ (sr & 7)) * 8;

    float m_ = -INFINITY, l_ = 0.f;               // state for q-row (w*16 + c), log2 domain
    f32x4 o[4] = {};                              // O[q = g*4+r][d = go*16+c]

    for (int kt = 0; kt < ktend; kt += 64) {
        __syncthreads();
        gload_lds16(&K[(bh * TT + kt + sr) * DKK + scol], &Ks[tid * 8]);
        gload_lds16(&Vt[(bh * DKK + sr) * TT + kt + scol], &Vs[tid * 8]);
        __syncthreads();  // drains vmcnt(0)

        f32x4 s[4] = {};
        __builtin_amdgcn_s_setprio(1);
#pragma unroll
        for (int j = 0; j < 4; j++)
#pragma unroll
            for (int half = 0; half < 2; half++) {
                bf16x8 kf = *(bf16x8*)((char*)Ks + (j * 16 + c) * 128 +
                                       (((unsigned)(half * 64 + g * 16)) ^ swz));
                s[j] = __builtin_amdgcn_mfma_f32_16x16x32_bf16(kf, qf[half], s[j], 0, 0, 0);
            }
        __builtin_amdgcn_s_setprio(0);
        // s[j][r] = z[kv = kt+j*16+g*4+r][q], already scaled by 0.125*log2e

        if (kt + 64 > sl) {                       // partial/masked tile only (block-uniform)
#pragma unroll
            for (int j = 0; j < 4; j++) {
                int kbase = kt + j * 16 + g * 4;
#pragma unroll
                for (int r = 0; r < 4; r++)
                    if (kbase + r >= sl) s[j][r] = -14427.0f;  // ~ -10000*log2e; exp2 -> 0
            }
        }

        float tmax = -INFINITY;
#pragma unroll
        for (int j = 0; j < 4; j++)
#pragma unroll
            for (int r = 0; r < 4; r++) tmax = fmaxf(tmax, s[j][r]);
        tmax = fmaxf(tmax, __shfl_xor(tmax, 16));
        tmax = fmaxf(tmax, __shfl_xor(tmax, 32));

        float p[4][4];
        float ps = 0.f;
        if (__all(tmax <= m_ + 8.f)) {
            // deferred: keep m_, skip alpha/rescale; p bounded by 2^8
#pragma unroll
            for (int j = 0; j < 4; j++)
#pragma unroll
                for (int r = 0; r < 4; r++) {
                    p[j][r] = __builtin_amdgcn_exp2f(s[j][r] - m_);
                    ps += p[j][r];
                }
            ps += __shfl_xor(ps, 16);
            ps += __shfl_xor(ps, 32);
            l_ += ps;
        } else {
            float mn = fmaxf(m_, tmax);
            float alpha = __builtin_amdgcn_exp2f(m_ - mn);
#pragma unroll
            for (int j = 0; j < 4; j++)
#pragma unroll
                for (int r = 0; r < 4; r++) {
                    p[j][r] = __builtin_amdgcn_exp2f(s[j][r] - mn);
                    ps += p[j][r];
                }
            ps += __shfl_xor(ps, 16);
            ps += __shfl_xor(ps, 32);
            l_ = l_ * alpha + ps;
            m_ = mn;
            float av[4];
#pragma unroll
            for (int r = 0; r < 4; r++) av[r] = __shfl(alpha, g * 4 + r);
#pragma unroll
            for (int go = 0; go < 4; go++)
#pragma unroll
                for (int r = 0; r < 4; r++) o[go][r] *= av[r];
        }

        // write P[q=c][kv = j*16+g*4 .. +3] as one b64, XOR-swizzled
#pragma unroll
        for (int j = 0; j < 4; j++) {
            __hip_bfloat162 lo = __float22bfloat162_rn(make_float2(p[j][0], p[j][1]));
            __hip_bfloat162 hi = __float22bfloat162_rn(make_float2(p[j][2], p[j][3]));
            uint2 u;
            u.x = *(unsigned*)&lo;
            u.y = *(unsigned*)&hi;
            *(uint2*)(Pw + c * 128 + (((unsigned)(j * 32 + g * 8)) ^ swz)) = u;
        }
        // read A-fragments: P[q=c][kv = half*32 + g*8 .. +7] (same-wave dep)
        bf16x8 pf0 = *(bf16x8*)(Pw + c * 128 + (((unsigned)(g * 16)) ^ swz));
        bf16x8 pf1 = *(bf16x8*)(Pw + c * 128 + (((unsigned)(64 + g * 16)) ^ swz));

        __builtin_amdgcn_s_setprio(1);
#pragma unroll
        for (int go = 0; go < 4; go++) {
            bf16x8 vf0 = *(bf16x8*)((char*)Vs + (go * 16 + c) * 128 +
                                    (((unsigned)(g * 16)) ^ swz));
            o[go] = __builtin_amdgcn_mfma_f32_16x16x32_bf16(pf0, vf0, o[go], 0, 0, 0);
            bf16x8 vf1 = *(bf16x8*)((char*)Vs + (go * 16 + c) * 128 +
                                    (((unsigned)(64 + g * 16)) ^ swz));
            o[go] = __builtin_amdgcn_mfma_f32_16x16x32_bf16(pf1, vf1, o[go], 0, 0, 0);
        }
        __builtin_amdgcn_s_setprio(0);
    }

    // final divide: l for q = g*4+r lives at lane (g*4+r)
    float linv[4];
#pragma unroll
    for (int r = 0; r < 4; r++) linv[r] = 1.f / __shfl(l_, g * 4 + r);
#pragma unroll
    for (int go = 0; go < 4; go++)
#pragma unroll
        for (int r = 0; r < 4; r++) {
            int t = q0 + w * 16 + g * 4 + r;
            int col = h * DKK + go * 16 + c;
            ctx[((size_t)(b * TT + t)) * HH + col] = f2bf(o[go][r] * linv[r]);
        }
}

// ---------------- row LayerNorm in-place on d_out (fp32), eps=1e-12 ----------------
__global__ __launch_bounds__(256) void ln_kernel(float* __restrict__ x,
                                                 const float* __restrict__ gam,
                                                 const float* __restrict__ bet) {
    int row = blockIdx.x, tid = threadIdx.x;
    float4 v = reinterpret_cast<float4*>(x)[(size_t)row * 256 + tid];
    float s = v.x + v.y + v.z + v.w;
#pragma unroll
    for (int m = 1; m < 64; m <<= 1) s += __shfl_xor(s, m);
    __shared__ float red[4], red2[4];
    if ((tid & 63) == 0) red[tid >> 6] = s;
    __syncthreads();
    float mean = (red[0] + red[1] + red[2] + red[3]) * (1.f / 1024.f);
    float dx0 = v.x - mean, dx1 = v.y - mean, dx2 = v.z - mean, dx3 = v.w - mean;
    float ss = dx0 * dx0 + dx1 * dx1 + dx2 * dx2 + dx3 * dx3;
#pragma unroll
    for (int m = 1; m < 64; m <<= 1) ss += __shfl_xor(ss, m);
    if ((tid & 63) == 0) red2[tid >> 6] = ss;
    __syncthreads();
    float var = (red2[0] + red2[1] + red2[2] + red2[3]) * (1.f / 1024.f);
    float rs = rsqrtf(var + 1e-12f);
    int c = tid * 4;
    float4 ov;
    ov.x = dx0 * rs * gam[c + 0] + bet[c + 0];
    ov.y = dx1 * rs * gam[c + 1] + bet[c + 1];
    ov.z = dx2 * rs * gam[c + 2] + bet[c + 2];
    ov.w = dx3 * rs * gam[c + 3] + bet[c + 3];
    reinterpret_cast<float4*>(x)[(size_t)row * 256 + tid] = ov;
}

extern "C" void kernel_launch(void* const* d_in, const int* in_sizes, int n_in,
                              void* d_out, int out_size, void* d_ws, size_t ws_size,
                              hipStream_t stream) {
    const float* hid  = (const float*)d_in[0];
    const float* src  = (const float*)d_in[1];
    const int* slen   = (const int*)d_in[2];   // harness passes integers as int32
    const float* Wq  = (const float*)d_in[3];  const float* bq  = (const float*)d_in[4];
    const float* Wk  = (const float*)d_in[5];  const float* bk  = (const float*)d_in[6];
    const float* Wv  = (const float*)d_in[7];  const float* bv  = (const float*)d_in[8];
    const float* Wd  = (const float*)d_in[9];  const float* bd  = (const float*)d_in[10];
    const float* Wp1 = (const float*)d_in[11]; const float* bp1 = (const float*)d_in[12];
    const float* Wp2 = (const float*)d_in[13]; const float* bp2 = (const float*)d_in[14];
    const float* lng = (const float*)d_in[15]; const float* lnb = (const float*)d_in[16];

    // Workspace layout (bytes). Needs 92 MB.
    char* ws = (char*)d_ws;
    const size_t MB = 1ull << 20;
    unsigned short* Wqt  = (unsigned short*)(ws + 0 * MB);
    unsigned short* Wkt  = (unsigned short*)(ws + 2 * MB);
    unsigned short* Wvt  = (unsigned short*)(ws + 4 * MB);
    unsigned short* Wdt  = (unsigned short*)(ws + 6 * MB);
    unsigned short* Wp1t = (unsigned short*)(ws + 8 * MB);
    unsigned short* Wp2t = (unsigned short*)(ws + 10 * MB);
    unsigned short* hidb = (unsigned short*)(ws + 12 * MB);  // later aliased as Kb
    unsigned short* srcb = (unsigned short*)(ws + 28 * MB);  // later aliased as ctx
    unsigned short* Ptmp = (unsigned short*)(ws + 44 * MB);  // later aliased as Vtb
    unsigned short* Pb   = (unsigned short*)(ws + 60 * MB);
    unsigned short* Qb   = (unsigned short*)(ws + 76 * MB);
    unsigned short* Kb   = hidb;
    unsigned short* Vtb  = Ptmp;
    unsigned short* ctxb = srcb;

    dim3 tb(32, 8);
    wtcvt_kernel<<<dim3(32, 32), tb, 0, stream>>>(Wq, Wqt);
    wtcvt_kernel<<<dim3(32, 32), tb, 0, stream>>>(Wk, Wkt);
    wtcvt_kernel<<<dim3(32, 32), tb, 0, stream>>>(Wv, Wvt);
    wtcvt_kernel<<<dim3(32, 32), tb, 0, stream>>>(Wd, Wdt);
    wtcvt_kernel<<<dim3(32, 32), tb, 0, stream>>>(Wp1, Wp1t);
    wtcvt_kernel<<<dim3(32, 32), tb, 0, stream>>>(Wp2, Wp2t);

    const int n4 = (BB * TT * HH) / 4;  // 2M float4s
    cvt_kernel<<<n4 / 256, 256, 0, stream>>>(hid, hidb, n4);
    cvt_kernel<<<n4 / 256, 256, 0, stream>>>(src, srcb, n4);

    dim3 gg(HH / 128, (BB * TT) / 128);  // (8, 64)
    // P = mask(relu(src@Wp1+bp1)@Wp2+bp2); rows >= ceil64(sl) are dead -> SKIP
    gemm_kernel<1, true><<<gg, 256, 0, stream>>>(srcb, Wp1t, bp1, Ptmp, nullptr, nullptr, slen, BB * TT, HH, HH);
    gemm_kernel<2, true><<<gg, 256, 0, stream>>>(Ptmp, Wp2t, bp2, Pb, nullptr, nullptr, slen, BB * TT, HH, HH);
    // Q (pre-scaled for base-2 softmax) all rows; K,V only live rows
    gemm_kernel<6, false><<<gg, 256, 0, stream>>>(hidb, Wqt, bq, Qb, nullptr, nullptr, slen, BB * TT, HH, HH);
    gemm_kernel<3, true><<<gg, 256, 0, stream>>>(Pb, Wkt, bk, Kb, nullptr, nullptr, slen, BB * TT, HH, HH);
    gemm_kernel<4, true><<<gg, 256, 0, stream>>>(Pb, Wvt, bv, Vtb, nullptr, nullptr, slen, BB * TT, HH, HH);
    // attention -> ctx (B,T,H) bf16
    attn_kernel<<<dim3(TT / 128, NHH, BB), 512, 0, stream>>>(Qb, Kb, Vtb, slen, ctxb);
    // x = ctx@Wd + bd + hidden -> d_out fp32
    gemm_kernel<5, false><<<gg, 256, 0, stream>>>(ctxb, Wdt, bd, nullptr, (float*)d_out, hid, slen, BB * TT, HH, HH);
    // LayerNorm in place
    ln_kernel<<<BB * TT, 256, 0, stream>>>((float*)d_out, lng, lnb);
}

// Round 7
// 272.666 us; speedup vs baseline: 1.9868x; 1.0492x over previous
//
#include <hip/hip_runtime.h>
#include <hip/hip_bf16.h>

// Problem dims (fixed by the reference)
#define BB 4
#define TT 2048
#define HH 1024
#define NHH 16
#define DKK 64
// M = BB*TT = 8192, K = N = HH = 1024

typedef __attribute__((ext_vector_type(8))) short bf16x8;
typedef __attribute__((ext_vector_type(4))) float f32x4;

__device__ __forceinline__ unsigned short f2bf(float f) {
    union { float f; unsigned u; } v; v.f = f;
    unsigned r = v.u + 0x7fffu + ((v.u >> 16) & 1u);  // RNE
    return (unsigned short)(r >> 16);
}

// async global->LDS, 16B per lane; LDS dest must be linear in lane order
__device__ __forceinline__ void gload_lds16(const unsigned short* g, unsigned short* l) {
    __builtin_amdgcn_global_load_lds(
        (const __attribute__((address_space(1))) unsigned int*)g,
        (__attribute__((address_space(3))) unsigned int*)l, 16, 0, 0);
}

// ---------------- fp32 -> bf16 elementwise convert, 2 tensors in one dispatch ----------------
__global__ __launch_bounds__(256) void cvt2_kernel(const float* __restrict__ in0,
                                                   const float* __restrict__ in1,
                                                   unsigned short* __restrict__ out0,
                                                   unsigned short* __restrict__ out1, int n4) {
    const float* in = blockIdx.y ? in1 : in0;
    unsigned short* out = blockIdx.y ? out1 : out0;
    int i = blockIdx.x * blockDim.x + threadIdx.x;
    if (i < n4) {
        float4 v = reinterpret_cast<const float4*>(in)[i];
        union { unsigned short u[4]; unsigned long long ll; } o;
        o.u[0] = f2bf(v.x); o.u[1] = f2bf(v.y); o.u[2] = f2bf(v.z); o.u[3] = f2bf(v.w);
        reinterpret_cast<unsigned long long*>(out)[i] = o.ll;
    }
}

// ---------------- weight transpose + convert, all 6 weights in one dispatch ----------------
__global__ __launch_bounds__(256) void wtcvt6_kernel(
    const float* __restrict__ W0, const float* __restrict__ W1, const float* __restrict__ W2,
    const float* __restrict__ W3, const float* __restrict__ W4, const float* __restrict__ W5,
    unsigned short* __restrict__ T0, unsigned short* __restrict__ T1, unsigned short* __restrict__ T2,
    unsigned short* __restrict__ T3, unsigned short* __restrict__ T4, unsigned short* __restrict__ T5) {
    const float* W; unsigned short* Wt;
    switch (blockIdx.z) {
        case 0: W = W0; Wt = T0; break;
        case 1: W = W1; Wt = T1; break;
        case 2: W = W2; Wt = T2; break;
        case 3: W = W3; Wt = T3; break;
        case 4: W = W4; Wt = T4; break;
        default: W = W5; Wt = T5; break;
    }
    __shared__ float t[32][33];
    int bx = blockIdx.x * 32, by = blockIdx.y * 32;
    int tx = threadIdx.x, ty = threadIdx.y;   // block (32,8)
#pragma unroll
    for (int i = 0; i < 32; i += 8)
        t[ty + i][tx] = W[(size_t)(by + ty + i) * HH + bx + tx];
    __syncthreads();
#pragma unroll
    for (int i = 0; i < 32; i += 8)
        Wt[(size_t)(bx + ty + i) * HH + by + tx] = f2bf(t[tx][ty + i]);
}

// ---------------- MFMA GEMM (m97 structure): 128x128 tile, BK=64, global_load_lds w=16 ----------------
// EPI: 1=relu->bf16  2=source-mask->bf16  5=+resid fp32 out
template <int EPI, bool SKIP>
__global__ __launch_bounds__(256) void gemm_kernel(
    const unsigned short* __restrict__ A, const unsigned short* __restrict__ Bt,
    const float* __restrict__ bias, unsigned short* __restrict__ Cb,
    float* __restrict__ Cf, const float* __restrict__ resid,
    const int* __restrict__ slen, int M, int N, int K) {
    __shared__ unsigned short As[128 * 64];   // [row][k] linear (global_load_lds needs no pad)
    __shared__ unsigned short Bs[128 * 64];
    int by = blockIdx.y * 128, bx = blockIdx.x * 128;
    if constexpr (SKIP) {
        int slb = slen[by >> 11];
        int ktend = ((slb + 63) >> 6) << 6;
        if (ktend == 0) ktend = 64;           // attention still reads tile 0 (uniform-softmax case)
        if ((by & (TT - 1)) >= ktend) return; // whole 128-row tile dead (2048 % 128 == 0)
    }
    int tid = threadIdx.x, lane = tid & 63, w = tid >> 6;
    int wr = (w >> 1) * 64, wc = (w & 1) * 64;     // wave's 64x64 output quadrant

    f32x4 acc[4][4] = {};
    for (int k0 = 0; k0 < K; k0 += 64) {
        __syncthreads();
#pragma unroll
        for (int c = 0; c < 4; c++) {
            int idx = c * 256 + tid;
            int r = idx >> 3, col = (idx & 7) * 8;
            gload_lds16(&A[(size_t)(by + r) * K + k0 + col], &As[idx * 8]);
            gload_lds16(&Bt[(size_t)(bx + r) * K + k0 + col], &Bs[idx * 8]);
        }
        __syncthreads();  // compiler drains vmcnt(0) here (global_load_lds complete)
#pragma unroll
        for (int kk = 0; kk < 2; kk++) {
            bf16x8 a[4], b[4];
#pragma unroll
            for (int i = 0; i < 4; i++)
                a[i] = *(bf16x8*)&As[(wr + i * 16 + (lane & 15)) * 64 + kk * 32 + (lane >> 4) * 8];
#pragma unroll
            for (int j = 0; j < 4; j++)
                b[j] = *(bf16x8*)&Bs[(wc + j * 16 + (lane & 15)) * 64 + kk * 32 + (lane >> 4) * 8];
#pragma unroll
            for (int i = 0; i < 4; i++)
#pragma unroll
                for (int j = 0; j < 4; j++)
                    acc[i][j] = __builtin_amdgcn_mfma_f32_16x16x32_bf16(a[i], b[j], acc[i][j], 0, 0, 0);
        }
    }

    int sl = 0;
    if constexpr (EPI == 2) sl = slen[by >> 11];  // 128-row tile never crosses a batch
#pragma unroll
    for (int i = 0; i < 4; i++)
#pragma unroll
        for (int j = 0; j < 4; j++)
#pragma unroll
            for (int r = 0; r < 4; r++) {
                int row = by + wr + i * 16 + (lane >> 4) * 4 + r;
                int col = bx + wc + j * 16 + (lane & 15);
                float v = acc[i][j][r] + bias[col];
                if constexpr (EPI == 1) v = fmaxf(v, 0.f);
                if constexpr (EPI == 2) { int t = row & (TT - 1); if (t >= sl) v = 0.f; }
                if constexpr (EPI == 1 || EPI == 2) {
                    Cb[(size_t)row * N + col] = f2bf(v);
                } else if constexpr (EPI == 5) {
                    Cf[(size_t)row * N + col] = v + resid[(size_t)row * N + col];
                }
            }
}

// ---------------- fused Q/K/V projection: one dispatch, blockIdx.x sector picks the GEMM ----------------
// sector 0: Q = hidb@Wq + bq, *0.125*log2e, head-split store (no skip)
// sector 1: K = Pb@Wk + bk, head-split store (dead-tile skip)
// sector 2: V = Pb@Wv + bv, transposed-head store (dead-tile skip)
__global__ __launch_bounds__(256) void qkv_gemm_kernel(
    const unsigned short* __restrict__ hidb, const unsigned short* __restrict__ Pb,
    const unsigned short* __restrict__ Wqt, const unsigned short* __restrict__ Wkt,
    const unsigned short* __restrict__ Wvt,
    const float* __restrict__ bq, const float* __restrict__ bk, const float* __restrict__ bv,
    unsigned short* __restrict__ Qb, unsigned short* __restrict__ Kb,
    unsigned short* __restrict__ Vtb, const int* __restrict__ slen) {
    __shared__ unsigned short As[128 * 64];
    __shared__ unsigned short Bs[128 * 64];
    int sector = blockIdx.x >> 3;
    int bx = (blockIdx.x & 7) * 128;
    int by = blockIdx.y * 128;
    int slb = slen[by >> 11];
    int ktend = ((slb + 63) >> 6) << 6;
    if (ktend == 0) ktend = 64;
    if (sector != 0 && (by & (TT - 1)) >= ktend) return;  // K/V rows dead

    const unsigned short* A  = (sector == 0) ? hidb : Pb;
    const unsigned short* Bt = (sector == 0) ? Wqt : ((sector == 1) ? Wkt : Wvt);
    const float* bias        = (sector == 0) ? bq : ((sector == 1) ? bk : bv);

    int tid = threadIdx.x, lane = tid & 63, w = tid >> 6;
    int wr = (w >> 1) * 64, wc = (w & 1) * 64;

    f32x4 acc[4][4] = {};
    for (int k0 = 0; k0 < HH; k0 += 64) {
        __syncthreads();
#pragma unroll
        for (int c = 0; c < 4; c++) {
            int idx = c * 256 + tid;
            int r = idx >> 3, col = (idx & 7) * 8;
            gload_lds16(&A[(size_t)(by + r) * HH + k0 + col], &As[idx * 8]);
            gload_lds16(&Bt[(size_t)(bx + r) * HH + k0 + col], &Bs[idx * 8]);
        }
        __syncthreads();
#pragma unroll
        for (int kk = 0; kk < 2; kk++) {
            bf16x8 a[4], b[4];
#pragma unroll
            for (int i = 0; i < 4; i++)
                a[i] = *(bf16x8*)&As[(wr + i * 16 + (lane & 15)) * 64 + kk * 32 + (lane >> 4) * 8];
#pragma unroll
            for (int j = 0; j < 4; j++)
                b[j] = *(bf16x8*)&Bs[(wc + j * 16 + (lane & 15)) * 64 + kk * 32 + (lane >> 4) * 8];
#pragma unroll
            for (int i = 0; i < 4; i++)
#pragma unroll
                for (int j = 0; j < 4; j++)
                    acc[i][j] = __builtin_amdgcn_mfma_f32_16x16x32_bf16(a[i], b[j], acc[i][j], 0, 0, 0);
        }
    }

#pragma unroll
    for (int i = 0; i < 4; i++)
#pragma unroll
        for (int j = 0; j < 4; j++)
#pragma unroll
            for (int r = 0; r < 4; r++) {
                int row = by + wr + i * 16 + (lane >> 4) * 4 + r;
                int col = bx + wc + j * 16 + (lane & 15);
                float v = acc[i][j][r] + bias[col];
                int b = row >> 11, t = row & (TT - 1), h = col >> 6, d = col & 63;
                if (sector == 0) {
                    v *= 0.18033688f;   // 0.125 * log2(e), feeds base-2 softmax
                    Qb[((size_t)((b * NHH + h) * TT + t)) * DKK + d] = f2bf(v);
                } else if (sector == 1) {
                    Kb[((size_t)((b * NHH + h) * TT + t)) * DKK + d] = f2bf(v);
                } else {
                    Vtb[((size_t)((b * NHH + h) * DKK + d)) * TT + t] = f2bf(v);
                }
            }
}

// ---------------- flash attention: block = (b, h, 128 q-rows), 8 waves x 16 q-rows ----------------
// Swapped QK^T (lane owns one q-row), base-2 softmax, full-tile mask skip, T13 defer-max,
// K/V double-buffered: tile t+1's global_load_lds issued right after the barrier so the next
// barrier's vmcnt-drain waits on loads that had the whole compute phase to land.
__global__ __launch_bounds__(512) void attn_kernel(
    const unsigned short* __restrict__ Q, const unsigned short* __restrict__ K,
    const unsigned short* __restrict__ Vt, const int* __restrict__ slen,
    unsigned short* __restrict__ ctx) {
    __shared__ unsigned short Ks[2][64 * 64];     // [kv][dk], XOR-swizzled content
    __shared__ unsigned short Vs[2][64 * 64];     // [dk][kv], XOR-swizzled content
    __shared__ unsigned short Pl[8][16 * 64];     // per-wave P [q][kv], XOR-swizzled
    int tid = threadIdx.x, lane = tid & 63, w = tid >> 6;
    int c = lane & 15, g = lane >> 4;
    int b = blockIdx.z, h = blockIdx.y, q0 = blockIdx.x * 128;
    size_t bh = (size_t)(b * NHH + h);
    int sl = slen[b];
    int ktend = ((sl + 63) >> 6) << 6;
    if (ktend == 0) ktend = 64;                   // all-masked: one tile, uniform softmax -> bv

    bf16x8 qf[2];                                 // B-operand: Q[q = w*16+c][dk]
    int qrow = q0 + w * 16 + c;
#pragma unroll
    for (int half = 0; half < 2; half++)
        qf[half] = *(const bf16x8*)&Q[(bh * TT + qrow) * DKK + half * 32 + g * 8];

    char* Pw = (char*)&Pl[w][0];
    unsigned swz = (unsigned)((c & 7) << 4);

    // staging coords: thread stages chunk (r = tid>>3, slot = tid&7) of both K and V;
    // source slot pre-swizzled so LDS[r][s] = G[r][s ^ (r&7)]
    int sr = tid >> 3, ss = tid & 7;
    int scol = (ss ^ (sr & 7)) * 8;

    // prologue: issue tile-0 loads into buffer 0
    gload_lds16(&K[(bh * TT + sr) * DKK + scol], &Ks[0][tid * 8]);
    gload_lds16(&Vt[(bh * DKK + sr) * TT + scol], &Vs[0][tid * 8]);
    int cur = 0;

    float m_ = -INFINITY, l_ = 0.f;               // state for q-row (w*16 + c), log2 domain
    f32x4 o[4] = {};                              // O[q = g*4+r][d = go*16+c]

    for (int kt = 0; kt < ktend; kt += 64) {
        __syncthreads();   // drains vmcnt -> buf[cur] ready; all waves done reading buf[cur^1]
        if (kt + 64 < ktend) {                    // prefetch next tile into the other buffer
            gload_lds16(&K[(bh * TT + kt + 64 + sr) * DKK + scol], &Ks[cur ^ 1][tid * 8]);
            gload_lds16(&Vt[(bh * DKK + sr) * TT + kt + 64 + scol], &Vs[cur ^ 1][tid * 8]);
        }

        f32x4 s[4] = {};
        __builtin_amdgcn_s_setprio(1);
#pragma unroll
        for (int j = 0; j < 4; j++)
#pragma unroll
            for (int half = 0; half < 2; half++) {
                bf16x8 kf = *(bf16x8*)((char*)&Ks[cur][0] + (j * 16 + c) * 128 +
                                       (((unsigned)(half * 64 + g * 16)) ^ swz));
                s[j] = __builtin_amdgcn_mfma_f32_16x16x32_bf16(kf, qf[half], s[j], 0, 0, 0);
            }
        __builtin_amdgcn_s_setprio(0);
        // s[j][r] = z[kv = kt+j*16+g*4+r][q], already scaled by 0.125*log2e

        if (kt + 64 > sl) {                       // partial/masked tile only (block-uniform)
#pragma unroll
            for (int j = 0; j < 4; j++) {
                int kbase = kt + j * 16 + g * 4;
#pragma unroll
                for (int r = 0; r < 4; r++)
                    if (kbase + r >= sl) s[j][r] = -14427.0f;  // ~ -10000*log2e; exp2 -> 0
            }
        }

        float tmax = -INFINITY;
#pragma unroll
        for (int j = 0; j < 4; j++)
#pragma unroll
            for (int r = 0; r < 4; r++) tmax = fmaxf(tmax, s[j][r]);
        tmax = fmaxf(tmax, __shfl_xor(tmax, 16));
        tmax = fmaxf(tmax, __shfl_xor(tmax, 32));

        float p[4][4];
        float ps = 0.f;
        if (__all(tmax <= m_ + 8.f)) {
            // deferred: keep m_, skip alpha/rescale; p bounded by 2^8
#pragma unroll
            for (int j = 0; j < 4; j++)
#pragma unroll
                for (int r = 0; r < 4; r++) {
                    p[j][r] = __builtin_amdgcn_exp2f(s[j][r] - m_);
                    ps += p[j][r];
                }
            ps += __shfl_xor(ps, 16);
            ps += __shfl_xor(ps, 32);
            l_ += ps;
        } else {
            float mn = fmaxf(m_, tmax);
            float alpha = __builtin_amdgcn_exp2f(m_ - mn);
#pragma unroll
            for (int j = 0; j < 4; j++)
#pragma unroll
                for (int r = 0; r < 4; r++) {
                    p[j][r] = __builtin_amdgcn_exp2f(s[j][r] - mn);
                    ps += p[j][r];
                }
            ps += __shfl_xor(ps, 16);
            ps += __shfl_xor(ps, 32);
            l_ = l_ * alpha + ps;
            m_ = mn;
            float av[4];
#pragma unroll
            for (int r = 0; r < 4; r++) av[r] = __shfl(alpha, g * 4 + r);
#pragma unroll
            for (int go = 0; go < 4; go++)
#pragma unroll
                for (int r = 0; r < 4; r++) o[go][r] *= av[r];
        }

        // write P[q=c][kv = j*16+g*4 .. +3] as one b64, XOR-swizzled
#pragma unroll
        for (int j = 0; j < 4; j++) {
            __hip_bfloat162 lo = __float22bfloat162_rn(make_float2(p[j][0], p[j][1]));
            __hip_bfloat162 hi = __float22bfloat162_rn(make_float2(p[j][2], p[j][3]));
            uint2 u;
            u.x = *(unsigned*)&lo;
            u.y = *(unsigned*)&hi;
            *(uint2*)(Pw + c * 128 + (((unsigned)(j * 32 + g * 8)) ^ swz)) = u;
        }
        // read A-fragments: P[q=c][kv = half*32 + g*8 .. +7] (same-wave dep)
        bf16x8 pf0 = *(bf16x8*)(Pw + c * 128 + (((unsigned)(g * 16)) ^ swz));
        bf16x8 pf1 = *(bf16x8*)(Pw + c * 128 + (((unsigned)(64 + g * 16)) ^ swz));

        __builtin_amdgcn_s_setprio(1);
#pragma unroll
        for (int go = 0; go < 4; go++) {
            bf16x8 vf0 = *(bf16x8*)((char*)&Vs[cur][0] + (go * 16 + c) * 128 +
                                    (((unsigned)(g * 16)) ^ swz));
            o[go] = __builtin_amdgcn_mfma_f32_16x16x32_bf16(pf0, vf0, o[go], 0, 0, 0);
            bf16x8 vf1 = *(bf16x8*)((char*)&Vs[cur][0] + (go * 16 + c) * 128 +
                                    (((unsigned)(64 + g * 16)) ^ swz));
            o[go] = __builtin_amdgcn_mfma_f32_16x16x32_bf16(pf1, vf1, o[go], 0, 0, 0);
        }
        __builtin_amdgcn_s_setprio(0);
        cur ^= 1;
    }

    // final divide: l for q = g*4+r lives at lane (g*4+r)
    float linv[4];
#pragma unroll
    for (int r = 0; r < 4; r++) linv[r] = 1.f / __shfl(l_, g * 4 + r);
#pragma unroll
    for (int go = 0; go < 4; go++)
#pragma unroll
        for (int r = 0; r < 4; r++) {
            int t = q0 + w * 16 + g * 4 + r;
            int col = h * DKK + go * 16 + c;
            ctx[((size_t)(b * TT + t)) * HH + col] = f2bf(o[go][r] * linv[r]);
        }
}

// ---------------- row LayerNorm in-place on d_out (fp32), eps=1e-12 ----------------
__global__ __launch_bounds__(256) void ln_kernel(float* __restrict__ x,
                                                 const float* __restrict__ gam,
                                                 const float* __restrict__ bet) {
    int row = blockIdx.x, tid = threadIdx.x;
    float4 v = reinterpret_cast<float4*>(x)[(size_t)row * 256 + tid];
    float s = v.x + v.y + v.z + v.w;
#pragma unroll
    for (int m = 1; m < 64; m <<= 1) s += __shfl_xor(s, m);
    __shared__ float red[4], red2[4];
    if ((tid & 63) == 0) red[tid >> 6] = s;
    __syncthreads();
    float mean = (red[0] + red[1] + red[2] + red[3]) * (1.f / 1024.f);
    float dx0 = v.x - mean, dx1 = v.y - mean, dx2 = v.z - mean, dx3 = v.w - mean;
    float ss = dx0 * dx0 + dx1 * dx1 + dx2 * dx2 + dx3 * dx3;
#pragma unroll
    for (int m = 1; m < 64; m <<= 1) ss += __shfl_xor(ss, m);
    if ((tid & 63) == 0) red2[tid >> 6] = ss;
    __syncthreads();
    float var = (red2[0] + red2[1] + red2[2] + red2[3]) * (1.f / 1024.f);
    float rs = rsqrtf(var + 1e-12f);
    int c = tid * 4;
    float4 ov;
    ov.x = dx0 * rs * gam[c + 0] + bet[c + 0];
    ov.y = dx1 * rs * gam[c + 1] + bet[c + 1];
    ov.z = dx2 * rs * gam[c + 2] + bet[c + 2];
    ov.w = dx3 * rs * gam[c + 3] + bet[c + 3];
    reinterpret_cast<float4*>(x)[(size_t)row * 256 + tid] = ov;
}

extern "C" void kernel_launch(void* const* d_in, const int* in_sizes, int n_in,
                              void* d_out, int out_size, void* d_ws, size_t ws_size,
                              hipStream_t stream) {
    const float* hid  = (const float*)d_in[0];
    const float* src  = (const float*)d_in[1];
    const int* slen   = (const int*)d_in[2];   // harness passes integers as int32
    const float* Wq  = (const float*)d_in[3];  const float* bq  = (const float*)d_in[4];
    const float* Wk  = (const float*)d_in[5];  const float* bk  = (const float*)d_in[6];
    const float* Wv  = (const float*)d_in[7];  const float* bv  = (const float*)d_in[8];
    const float* Wd  = (const float*)d_in[9];  const float* bd  = (const float*)d_in[10];
    const float* Wp1 = (const float*)d_in[11]; const float* bp1 = (const float*)d_in[12];
    const float* Wp2 = (const float*)d_in[13]; const float* bp2 = (const float*)d_in[14];
    const float* lng = (const float*)d_in[15]; const float* lnb = (const float*)d_in[16];

    // Workspace layout (bytes). Needs 92 MB.
    char* ws = (char*)d_ws;
    const size_t MB = 1ull << 20;
    unsigned short* Wqt  = (unsigned short*)(ws + 0 * MB);
    unsigned short* Wkt  = (unsigned short*)(ws + 2 * MB);
    unsigned short* Wvt  = (unsigned short*)(ws + 4 * MB);
    unsigned short* Wdt  = (unsigned short*)(ws + 6 * MB);
    unsigned short* Wp1t = (unsigned short*)(ws + 8 * MB);
    unsigned short* Wp2t = (unsigned short*)(ws + 10 * MB);
    unsigned short* hidb = (unsigned short*)(ws + 12 * MB);  // later aliased as Kb
    unsigned short* srcb = (unsigned short*)(ws + 28 * MB);  // later aliased as ctx
    unsigned short* Ptmp = (unsigned short*)(ws + 44 * MB);  // later aliased as Vtb
    unsigned short* Pb   = (unsigned short*)(ws + 60 * MB);
    unsigned short* Qb   = (unsigned short*)(ws + 76 * MB);
    unsigned short* Kb   = hidb;
    unsigned short* Vtb  = Ptmp;
    unsigned short* ctxb = srcb;

    // all 6 weight transposes in one dispatch
    wtcvt6_kernel<<<dim3(32, 32, 6), dim3(32, 8), 0, stream>>>(
        Wq, Wk, Wv, Wd, Wp1, Wp2, Wqt, Wkt, Wvt, Wdt, Wp1t, Wp2t);

    // both activation converts in one dispatch
    const int n4 = (BB * TT * HH) / 4;  // 2M float4s
    cvt2_kernel<<<dim3(n4 / 256, 2), 256, 0, stream>>>(hid, src, hidb, srcb, n4);

    dim3 gg(HH / 128, (BB * TT) / 128);  // (8, 64)
    // P = mask(relu(src@Wp1+bp1)@Wp2+bp2); rows >= ceil64(sl) are dead -> SKIP
    gemm_kernel<1, true><<<gg, 256, 0, stream>>>(srcb, Wp1t, bp1, Ptmp, nullptr, nullptr, slen, BB * TT, HH, HH);
    gemm_kernel<2, true><<<gg, 256, 0, stream>>>(Ptmp, Wp2t, bp2, Pb, nullptr, nullptr, slen, BB * TT, HH, HH);
    // fused Q/K/V projections (Q pre-scaled for base-2 softmax; K/V skip dead rows)
    qkv_gemm_kernel<<<dim3(24, 64), 256, 0, stream>>>(
        hidb, Pb, Wqt, Wkt, Wvt, bq, bk, bv, Qb, Kb, Vtb, slen);
    // attention -> ctx (B,T,H) bf16
    attn_kernel<<<dim3(TT / 128, NHH, BB), 512, 0, stream>>>(Qb, Kb, Vtb, slen, ctxb);
    // x = ctx@Wd + bd + hidden -> d_out fp32
    gemm_kernel<5, false><<<gg, 256, 0, stream>>>(ctxb, Wdt, bd, nullptr, (float*)d_out, hid, slen, BB * TT, HH, HH);
    // LayerNorm in place
    ln_kernel<<<BB * TT, 256, 0, stream>>>((float*)d_out, lng, lnb);
}

// Round 8
// 269.488 us; speedup vs baseline: 2.0103x; 1.0118x over previous
//
#include <hip/hip_runtime.h>
#include <hip/hip_bf16.h>

// Problem dims (fixed by the reference)
#define BB 4
#define TT 2048
#define HH 1024
#define NHH 16
#define DKK 64
// M = BB*TT = 8192, K = N = HH = 1024

typedef __attribute__((ext_vector_type(8))) short bf16x8;
typedef __attribute__((ext_vector_type(4))) float f32x4;

__device__ __forceinline__ unsigned short f2bf(float f) {
    union { float f; unsigned u; } v; v.f = f;
    unsigned r = v.u + 0x7fffu + ((v.u >> 16) & 1u);  // RNE
    return (unsigned short)(r >> 16);
}

// async global->LDS, 16B per lane; LDS dest must be linear in lane order
__device__ __forceinline__ void gload_lds16(const unsigned short* g, unsigned short* l) {
    __builtin_amdgcn_global_load_lds(
        (const __attribute__((address_space(1))) unsigned int*)g,
        (__attribute__((address_space(3))) unsigned int*)l, 16, 0, 0);
}

// ---------------- fp32 -> bf16 elementwise convert, 2 tensors in one dispatch ----------------
__global__ __launch_bounds__(256) void cvt2_kernel(const float* __restrict__ in0,
                                                   const float* __restrict__ in1,
                                                   unsigned short* __restrict__ out0,
                                                   unsigned short* __restrict__ out1, int n4) {
    const float* in = blockIdx.y ? in1 : in0;
    unsigned short* out = blockIdx.y ? out1 : out0;
    int i = blockIdx.x * blockDim.x + threadIdx.x;
    if (i < n4) {
        float4 v = reinterpret_cast<const float4*>(in)[i];
        union { unsigned short u[4]; unsigned long long ll; } o;
        o.u[0] = f2bf(v.x); o.u[1] = f2bf(v.y); o.u[2] = f2bf(v.z); o.u[3] = f2bf(v.w);
        reinterpret_cast<unsigned long long*>(out)[i] = o.ll;
    }
}

// ---------------- weight transpose + convert, all 6 weights in one dispatch ----------------
__global__ __launch_bounds__(256) void wtcvt6_kernel(
    const float* __restrict__ W0, const float* __restrict__ W1, const float* __restrict__ W2,
    const float* __restrict__ W3, const float* __restrict__ W4, const float* __restrict__ W5,
    unsigned short* __restrict__ T0, unsigned short* __restrict__ T1, unsigned short* __restrict__ T2,
    unsigned short* __restrict__ T3, unsigned short* __restrict__ T4, unsigned short* __restrict__ T5) {
    const float* W; unsigned short* Wt;
    switch (blockIdx.z) {
        case 0: W = W0; Wt = T0; break;
        case 1: W = W1; Wt = T1; break;
        case 2: W = W2; Wt = T2; break;
        case 3: W = W3; Wt = T3; break;
        case 4: W = W4; Wt = T4; break;
        default: W = W5; Wt = T5; break;
    }
    __shared__ float t[32][33];
    int bx = blockIdx.x * 32, by = blockIdx.y * 32;
    int tx = threadIdx.x, ty = threadIdx.y;   // block (32,8)
#pragma unroll
    for (int i = 0; i < 32; i += 8)
        t[ty + i][tx] = W[(size_t)(by + ty + i) * HH + bx + tx];
    __syncthreads();
#pragma unroll
    for (int i = 0; i < 32; i += 8)
        Wt[(size_t)(bx + ty + i) * HH + by + tx] = f2bf(t[tx][ty + i]);
}

// ---------------- MFMA GEMM (m97 structure): 128x128 tile, BK=64, global_load_lds w=16 ----------------
// Grid is FIXED (8,64). XCD tile swizzle: all 8 column-blocks sharing an A row-panel get the same
// flat%8 -> same XCD -> the panel is filled into one L2, not eight.
// EPI: 1=relu->bf16  2=source-mask->bf16  3=head-split (K)  4=transposed-head (V)
//      5=+resid fp32 out  6=head-split * 0.125*log2e (Q, feeds base-2 softmax)
template <int EPI, bool SKIP>
__global__ __launch_bounds__(256) void gemm_kernel(
    const unsigned short* __restrict__ A, const unsigned short* __restrict__ Bt,
    const float* __restrict__ bias, unsigned short* __restrict__ Cb,
    float* __restrict__ Cf, const float* __restrict__ resid,
    const int* __restrict__ slen, int M, int N, int K) {
    __shared__ unsigned short As[128 * 64];   // [row][k] linear (global_load_lds needs no pad)
    __shared__ unsigned short Bs[128 * 64];
    // XCD swizzle (bijective for 8x64 grid): xcd = flat&7 owns rows {xcd, xcd+8, ...}
    int flat = blockIdx.y * 8 + blockIdx.x;
    int xcd = flat & 7, idx = flat >> 3;
    int bx = (idx & 7) * 128;
    int by = (xcd + ((idx >> 3) << 3)) * 128;
    if constexpr (SKIP) {
        int slb = slen[by >> 11];
        int ktend = ((slb + 63) >> 6) << 6;
        if (ktend == 0) ktend = 64;           // attention still reads tile 0 (uniform-softmax case)
        if ((by & (TT - 1)) >= ktend) return; // whole 128-row tile dead (2048 % 128 == 0)
    }
    int tid = threadIdx.x, lane = tid & 63, w = tid >> 6;
    int wr = (w >> 1) * 64, wc = (w & 1) * 64;     // wave's 64x64 output quadrant

    f32x4 acc[4][4] = {};
    for (int k0 = 0; k0 < K; k0 += 64) {
        __syncthreads();
#pragma unroll
        for (int c = 0; c < 4; c++) {
            int idx2 = c * 256 + tid;
            int r = idx2 >> 3, col = (idx2 & 7) * 8;
            gload_lds16(&A[(size_t)(by + r) * K + k0 + col], &As[idx2 * 8]);
            gload_lds16(&Bt[(size_t)(bx + r) * K + k0 + col], &Bs[idx2 * 8]);
        }
        __syncthreads();  // compiler drains vmcnt(0) here (global_load_lds complete)
#pragma unroll
        for (int kk = 0; kk < 2; kk++) {
            bf16x8 a[4], b[4];
#pragma unroll
            for (int i = 0; i < 4; i++)
                a[i] = *(bf16x8*)&As[(wr + i * 16 + (lane & 15)) * 64 + kk * 32 + (lane >> 4) * 8];
#pragma unroll
            for (int j = 0; j < 4; j++)
                b[j] = *(bf16x8*)&Bs[(wc + j * 16 + (lane & 15)) * 64 + kk * 32 + (lane >> 4) * 8];
#pragma unroll
            for (int i = 0; i < 4; i++)
#pragma unroll
                for (int j = 0; j < 4; j++)
                    acc[i][j] = __builtin_amdgcn_mfma_f32_16x16x32_bf16(a[i], b[j], acc[i][j], 0, 0, 0);
        }
    }

    int sl = 0;
    if constexpr (EPI == 2) sl = slen[by >> 11];  // 128-row tile never crosses a batch
#pragma unroll
    for (int i = 0; i < 4; i++)
#pragma unroll
        for (int j = 0; j < 4; j++)
#pragma unroll
            for (int r = 0; r < 4; r++) {
                int row = by + wr + i * 16 + (lane >> 4) * 4 + r;
                int col = bx + wc + j * 16 + (lane & 15);
                float v = acc[i][j][r] + bias[col];
                if constexpr (EPI == 1) v = fmaxf(v, 0.f);
                if constexpr (EPI == 2) { int t = row & (TT - 1); if (t >= sl) v = 0.f; }
                if constexpr (EPI == 6) v *= 0.18033688f;   // 0.125 * log2(e)
                if constexpr (EPI == 1 || EPI == 2) {
                    Cb[(size_t)row * N + col] = f2bf(v);
                } else if constexpr (EPI == 3 || EPI == 6) {
                    int b = row >> 11, t = row & (TT - 1), h = col >> 6, d = col & 63;
                    Cb[((size_t)((b * NHH + h) * TT + t)) * DKK + d] = f2bf(v);
                } else if constexpr (EPI == 4) {
                    int b = row >> 11, t = row & (TT - 1), h = col >> 6, d = col & 63;
                    Cb[((size_t)((b * NHH + h) * DKK + d)) * TT + t] = f2bf(v);
                } else if constexpr (EPI == 5) {
                    Cf[(size_t)row * N + col] = v + resid[(size_t)row * N + col];
                }
            }
}

// ---------------- flash attention: block = (b, h, 128 q-rows), 8 waves x 16 q-rows ----------------
// Swapped QK^T (lane owns one q-row), base-2 softmax, full-tile mask skip, T13 defer-max,
// K/V double-buffered: tile t+1's global_load_lds issued right after the barrier so the next
// barrier's vmcnt-drain waits on loads that had the whole compute phase to land.
__global__ __launch_bounds__(512) void attn_kernel(
    const unsigned short* __restrict__ Q, const unsigned short* __restrict__ K,
    const unsigned short* __restrict__ Vt, const int* __restrict__ slen,
    unsigned short* __restrict__ ctx) {
    __shared__ unsigned short Ks[2][64 * 64];     // [kv][dk], XOR-swizzled content
    __shared__ unsigned short Vs[2][64 * 64];     // [dk][kv], XOR-swizzled content
    __shared__ unsigned short Pl[8][16 * 64];     // per-wave P [q][kv], XOR-swizzled
    int tid = threadIdx.x, lane = tid & 63, w = tid >> 6;
    int c = lane & 15, g = lane >> 4;
    int b = blockIdx.z, h = blockIdx.y, q0 = blockIdx.x * 128;
    size_t bh = (size_t)(b * NHH + h);
    int sl = slen[b];
    int ktend = ((sl + 63) >> 6) << 6;
    if (ktend == 0) ktend = 64;                   // all-masked: one tile, uniform softmax -> bv

    bf16x8 qf[2];                                 // B-operand: Q[q = w*16+c][dk]
    int qrow = q0 + w * 16 + c;
#pragma unroll
    for (int half = 0; half < 2; half++)
        qf[half] = *(const bf16x8*)&Q[(bh * TT + qrow) * DKK + half * 32 + g * 8];

    char* Pw = (char*)&Pl[w][0];
    unsigned swz = (unsigned)((c & 7) << 4);

    // staging coords: thread stages chunk (r = tid>>3, slot = tid&7) of both K and V;
    // source slot pre-swizzled so LDS[r][s] = G[r][s ^ (r&7)]
    int sr = tid >> 3, ss = tid & 7;
    int scol = (ss ^ (sr & 7)) * 8;

    // prologue: issue tile-0 loads into buffer 0
    gload_lds16(&K[(bh * TT + sr) * DKK + scol], &Ks[0][tid * 8]);
    gload_lds16(&Vt[(bh * DKK + sr) * TT + scol], &Vs[0][tid * 8]);
    int cur = 0;

    float m_ = -INFINITY, l_ = 0.f;               // state for q-row (w*16 + c), log2 domain
    f32x4 o[4] = {};                              // O[q = g*4+r][d = go*16+c]

    for (int kt = 0; kt < ktend; kt += 64) {
        __syncthreads();   // drains vmcnt -> buf[cur] ready; all waves done reading buf[cur^1]
        if (kt + 64 < ktend) {                    // prefetch next tile into the other buffer
            gload_lds16(&K[(bh * TT + kt + 64 + sr) * DKK + scol], &Ks[cur ^ 1][tid * 8]);
            gload_lds16(&Vt[(bh * DKK + sr) * TT + kt + 64 + scol], &Vs[cur ^ 1][tid * 8]);
        }

        f32x4 s[4] = {};
        __builtin_amdgcn_s_setprio(1);
#pragma unroll
        for (int j = 0; j < 4; j++)
#pragma unroll
            for (int half = 0; half < 2; half++) {
                bf16x8 kf = *(bf16x8*)((char*)&Ks[cur][0] + (j * 16 + c) * 128 +
                                       (((unsigned)(half * 64 + g * 16)) ^ swz));
                s[j] = __builtin_amdgcn_mfma_f32_16x16x32_bf16(kf, qf[half], s[j], 0, 0, 0);
            }
        __builtin_amdgcn_s_setprio(0);
        // s[j][r] = z[kv = kt+j*16+g*4+r][q], already scaled by 0.125*log2e

        if (kt + 64 > sl) {                       // partial/masked tile only (block-uniform)
#pragma unroll
            for (int j = 0; j < 4; j++) {
                int kbase = kt + j * 16 + g * 4;
#pragma unroll
                for (int r = 0; r < 4; r++)
                    if (kbase + r >= sl) s[j][r] = -14427.0f;  // ~ -10000*log2e; exp2 -> 0
            }
        }

        float tmax = -INFINITY;
#pragma unroll
        for (int j = 0; j < 4; j++)
#pragma unroll
            for (int r = 0; r < 4; r++) tmax = fmaxf(tmax, s[j][r]);
        tmax = fmaxf(tmax, __shfl_xor(tmax, 16));
        tmax = fmaxf(tmax, __shfl_xor(tmax, 32));

        float p[4][4];
        float ps = 0.f;
        if (__all(tmax <= m_ + 8.f)) {
            // deferred: keep m_, skip alpha/rescale; p bounded by 2^8
#pragma unroll
            for (int j = 0; j < 4; j++)
#pragma unroll
                for (int r = 0; r < 4; r++) {
                    p[j][r] = __builtin_amdgcn_exp2f(s[j][r] - m_);
                    ps += p[j][r];
                }
            ps += __shfl_xor(ps, 16);
            ps += __shfl_xor(ps, 32);
            l_ += ps;
        } else {
            float mn = fmaxf(m_, tmax);
            float alpha = __builtin_amdgcn_exp2f(m_ - mn);
#pragma unroll
            for (int j = 0; j < 4; j++)
#pragma unroll
                for (int r = 0; r < 4; r++) {
                    p[j][r] = __builtin_amdgcn_exp2f(s[j][r] - mn);
                    ps += p[j][r];
                }
            ps += __shfl_xor(ps, 16);
            ps += __shfl_xor(ps, 32);
            l_ = l_ * alpha + ps;
            m_ = mn;
            float av[4];
#pragma unroll
            for (int r = 0; r < 4; r++) av[r] = __shfl(alpha, g * 4 + r);
#pragma unroll
            for (int go = 0; go < 4; go++)
#pragma unroll
                for (int r = 0; r < 4; r++) o[go][r] *= av[r];
        }

        // write P[q=c][kv = j*16+g*4 .. +3] as one b64, XOR-swizzled
#pragma unroll
        for (int j = 0; j < 4; j++) {
            __hip_bfloat162 lo = __float22bfloat162_rn(make_float2(p[j][0], p[j][1]));
            __hip_bfloat162 hi = __float22bfloat162_rn(make_float2(p[j][2], p[j][3]));
            uint2 u;
            u.x = *(unsigned*)&lo;
            u.y = *(unsigned*)&hi;
            *(uint2*)(Pw + c * 128 + (((unsigned)(j * 32 + g * 8)) ^ swz)) = u;
        }
        // read A-fragments: P[q=c][kv = half*32 + g*8 .. +7] (same-wave dep)
        bf16x8 pf0 = *(bf16x8*)(Pw + c * 128 + (((unsigned)(g * 16)) ^ swz));
        bf16x8 pf1 = *(bf16x8*)(Pw + c * 128 + (((unsigned)(64 + g * 16)) ^ swz));

        __builtin_amdgcn_s_setprio(1);
#pragma unroll
        for (int go = 0; go < 4; go++) {
            bf16x8 vf0 = *(bf16x8*)((char*)&Vs[cur][0] + (go * 16 + c) * 128 +
                                    (((unsigned)(g * 16)) ^ swz));
            o[go] = __builtin_amdgcn_mfma_f32_16x16x32_bf16(pf0, vf0, o[go], 0, 0, 0);
            bf16x8 vf1 = *(bf16x8*)((char*)&Vs[cur][0] + (go * 16 + c) * 128 +
                                    (((unsigned)(64 + g * 16)) ^ swz));
            o[go] = __builtin_amdgcn_mfma_f32_16x16x32_bf16(pf1, vf1, o[go], 0, 0, 0);
        }
        __builtin_amdgcn_s_setprio(0);
        cur ^= 1;
    }

    // final divide: l for q = g*4+r lives at lane (g*4+r)
    float linv[4];
#pragma unroll
    for (int r = 0; r < 4; r++) linv[r] = 1.f / __shfl(l_, g * 4 + r);
#pragma unroll
    for (int go = 0; go < 4; go++)
#pragma unroll
        for (int r = 0; r < 4; r++) {
            int t = q0 + w * 16 + g * 4 + r;
            int col = h * DKK + go * 16 + c;
            ctx[((size_t)(b * TT + t)) * HH + col] = f2bf(o[go][r] * linv[r]);
        }
}

// ---------------- row LayerNorm in-place on d_out (fp32), eps=1e-12 ----------------
__global__ __launch_bounds__(256) void ln_kernel(float* __restrict__ x,
                                                 const float* __restrict__ gam,
                                                 const float* __restrict__ bet) {
    int row = blockIdx.x, tid = threadIdx.x;
    float4 v = reinterpret_cast<float4*>(x)[(size_t)row * 256 + tid];
    float s = v.x + v.y + v.z + v.w;
#pragma unroll
    for (int m = 1; m < 64; m <<= 1) s += __shfl_xor(s, m);
    __shared__ float red[4], red2[4];
    if ((tid & 63) == 0) red[tid >> 6] = s;
    __syncthreads();
    float mean = (red[0] + red[1] + red[2] + red[3]) * (1.f / 1024.f);
    float dx0 = v.x - mean, dx1 = v.y - mean, dx2 = v.z - mean, dx3 = v.w - mean;
    float ss = dx0 * dx0 + dx1 * dx1 + dx2 * dx2 + dx3 * dx3;
#pragma unroll
    for (int m = 1; m < 64; m <<= 1) ss += __shfl_xor(ss, m);
    if ((tid & 63) == 0) red2[tid >> 6] = ss;
    __syncthreads();
    float var = (red2[0] + red2[1] + red2[2] + red2[3]) * (1.f / 1024.f);
    float rs = rsqrtf(var + 1e-12f);
    int c = tid * 4;
    float4 ov;
    ov.x = dx0 * rs * gam[c + 0] + bet[c + 0];
    ov.y = dx1 * rs * gam[c + 1] + bet[c + 1];
    ov.z = dx2 * rs * gam[c + 2] + bet[c + 2];
    ov.w = dx3 * rs * gam[c + 3] + bet[c + 3];
    reinterpret_cast<float4*>(x)[(size_t)row * 256 + tid] = ov;
}

extern "C" void kernel_launch(void* const* d_in, const int* in_sizes, int n_in,
                              void* d_out, int out_size, void* d_ws, size_t ws_size,
                              hipStream_t stream) {
    const float* hid  = (const float*)d_in[0];
    const float* src  = (const float*)d_in[1];
    const int* slen   = (const int*)d_in[2];   // harness passes integers as int32
    const float* Wq  = (const float*)d_in[3];  const float* bq  = (const float*)d_in[4];
    const float* Wk  = (const float*)d_in[5];  const float* bk  = (const float*)d_in[6];
    const float* Wv  = (const float*)d_in[7];  const float* bv  = (const float*)d_in[8];
    const float* Wd  = (const float*)d_in[9];  const float* bd  = (const float*)d_in[10];
    const float* Wp1 = (const float*)d_in[11]; const float* bp1 = (const float*)d_in[12];
    const float* Wp2 = (const float*)d_in[13]; const float* bp2 = (const float*)d_in[14];
    const float* lng = (const float*)d_in[15]; const float* lnb = (const float*)d_in[16];

    // Workspace layout (bytes). Needs 92 MB.
    char* ws = (char*)d_ws;
    const size_t MB = 1ull << 20;
    unsigned short* Wqt  = (unsigned short*)(ws + 0 * MB);
    unsigned short* Wkt  = (unsigned short*)(ws + 2 * MB);
    unsigned short* Wvt  = (unsigned short*)(ws + 4 * MB);
    unsigned short* Wdt  = (unsigned short*)(ws + 6 * MB);
    unsigned short* Wp1t = (unsigned short*)(ws + 8 * MB);
    unsigned short* Wp2t = (unsigned short*)(ws + 10 * MB);
    unsigned short* hidb = (unsigned short*)(ws + 12 * MB);  // later aliased as Kb
    unsigned short* srcb = (unsigned short*)(ws + 28 * MB);  // later aliased as ctx
    unsigned short* Ptmp = (unsigned short*)(ws + 44 * MB);  // later aliased as Vtb
    unsigned short* Pb   = (unsigned short*)(ws + 60 * MB);
    unsigned short* Qb   = (unsigned short*)(ws + 76 * MB);
    unsigned short* Kb   = hidb;
    unsigned short* Vtb  = Ptmp;
    unsigned short* ctxb = srcb;

    // all 6 weight transposes in one dispatch
    wtcvt6_kernel<<<dim3(32, 32, 6), dim3(32, 8), 0, stream>>>(
        Wq, Wk, Wv, Wd, Wp1, Wp2, Wqt, Wkt, Wvt, Wdt, Wp1t, Wp2t);

    // both activation converts in one dispatch
    const int n4 = (BB * TT * HH) / 4;  // 2M float4s
    cvt2_kernel<<<dim3(n4 / 256, 2), 256, 0, stream>>>(hid, src, hidb, srcb, n4);

    dim3 gg(8, 64);  // fixed (8,64) grid; in-kernel XCD tile swizzle
    // P = mask(relu(src@Wp1+bp1)@Wp2+bp2); rows >= ceil64(sl) are dead -> SKIP
    gemm_kernel<1, true><<<gg, 256, 0, stream>>>(srcb, Wp1t, bp1, Ptmp, nullptr, nullptr, slen, BB * TT, HH, HH);
    gemm_kernel<2, true><<<gg, 256, 0, stream>>>(Ptmp, Wp2t, bp2, Pb, nullptr, nullptr, slen, BB * TT, HH, HH);
    // Q (pre-scaled for base-2 softmax) all rows; K,V only live rows
    gemm_kernel<6, false><<<gg, 256, 0, stream>>>(hidb, Wqt, bq, Qb, nullptr, nullptr, slen, BB * TT, HH, HH);
    gemm_kernel<3, true><<<gg, 256, 0, stream>>>(Pb, Wkt, bk, Kb, nullptr, nullptr, slen, BB * TT, HH, HH);
    gemm_kernel<4, true><<<gg, 256, 0, stream>>>(Pb, Wvt, bv, Vtb, nullptr, nullptr, slen, BB * TT, HH, HH);
    // attention -> ctx (B,T,H) bf16
    attn_kernel<<<dim3(TT / 128, NHH, BB), 512, 0, stream>>>(Qb, Kb, Vtb, slen, ctxb);
    // x = ctx@Wd + bd + hidden -> d_out fp32
    gemm_kernel<5, false><<<gg, 256, 0, stream>>>(ctxb, Wdt, bd, nullptr, (float*)d_out, hid, slen, BB * TT, HH, HH);
    // LayerNorm in place
    ln_kernel<<<BB * TT, 256, 0, stream>>>((float*)d_out, lng, lnb);
}